// Round 1
// baseline (4348.392 us; speedup 1.0000x reference)
//
#include <hip/hip_runtime.h>
#include <math.h>

#define NB_ROWS 8192
#define DDIM 1024

#define BM 128
#define BN 128
#define BK 8

// (value desc, index asc) total order — matches jax.lax.top_k stability.
__device__ __forceinline__ bool pair_better(float s, int j, float v, int i) {
  return (s > v) || (s == v && j < i);
}

// ---------------- scan: bank2batch + query list per modality ----------------
// bank[j] = proj[order[j]] with order = stable argsort(~avail): available rows
// first, in original order. We only need the first Nb entries (bank2batch) and
// the list of query rows i (miss && i < Nb), whose sim row is bank row i.
__global__ void scan_kernel(const int* __restrict__ miss, int* __restrict__ meta,
                            int* __restrict__ b2b, int* __restrict__ qrw) {
  const int m = blockIdx.x, t = threadIdx.x, tmod = m + 1;
  __shared__ int cnt[256];
  const int base = t * 32;
  int c = 0;
  for (int i = 0; i < 32; ++i) c += (miss[base + i] != tmod) ? 1 : 0;
  cnt[t] = c; __syncthreads();
  for (int s = 1; s < 256; s <<= 1) {
    int v = (t >= s) ? cnt[t - s] : 0;
    __syncthreads();
    cnt[t] += v;
    __syncthreads();
  }
  const int Nb = cnt[255];
  int pos = cnt[t] - c;                      // exclusive prefix
  for (int i = 0; i < 32; ++i) {
    int r = base + i;
    if (miss[r] != tmod) b2b[m * NB_ROWS + (pos++)] = r;
  }
  __syncthreads();
  int q = 0;
  for (int i = 0; i < 32; ++i) {
    int r = base + i;
    q += (miss[r] == tmod && r < Nb) ? 1 : 0;
  }
  cnt[t] = q; __syncthreads();
  for (int s = 1; s < 256; s <<= 1) {
    int v = (t >= s) ? cnt[t - s] : 0;
    __syncthreads();
    cnt[t] += v;
    __syncthreads();
  }
  const int nQ = cnt[255];
  int qpos = cnt[t] - q;
  for (int i = 0; i < 32; ++i) {
    int r = base + i;
    if (miss[r] == tmod && r < Nb) qrw[m * 4096 + (qpos++)] = r;
  }
  if (t == 0) { meta[2 * m] = Nb; meta[2 * m + 1] = nQ; }
}

// ---------------- fp32 GEMM: C[M,1024] = A[M,K] @ B[K,1024] + bias ----------
__launch_bounds__(256)
__global__ void gemm_proj(const float* __restrict__ A, const float* __restrict__ Bw,
                          const float* __restrict__ bias, float* __restrict__ C,
                          int K) {
  __shared__ float As[BK][BM];
  __shared__ float Bs[BK][BN];
  const int t = threadIdx.x;
  const int n0 = blockIdx.x * BN, m0 = blockIdx.y * BM;
  const int tx = t & 15, ty = t >> 4;
  const int r0 = ty * 8, c0 = tx * 8;
  const int arow = t >> 1, akq = (t & 1) * 4;
  const int brow = t >> 5, bcol = (t & 31) * 4;
  float acc[8][8];
#pragma unroll
  for (int i = 0; i < 8; ++i)
#pragma unroll
    for (int j = 0; j < 8; ++j) acc[i][j] = 0.f;
  const float* Aptr = A + (size_t)(m0 + arow) * K + akq;
  const float* Bptr = Bw + (size_t)brow * DDIM + n0 + bcol;
  for (int k0 = 0; k0 < K; k0 += BK) {
    float4 av = *(const float4*)(Aptr + k0);
    float4 bv = *(const float4*)(Bptr + (size_t)k0 * DDIM);
    As[akq + 0][arow] = av.x; As[akq + 1][arow] = av.y;
    As[akq + 2][arow] = av.z; As[akq + 3][arow] = av.w;
    *(float4*)&Bs[brow][bcol] = bv;
    __syncthreads();
#pragma unroll
    for (int kk = 0; kk < BK; ++kk) {
      float a[8], b[8];
      *(float4*)&a[0] = *(const float4*)&As[kk][r0];
      *(float4*)&a[4] = *(const float4*)&As[kk][r0 + 4];
      *(float4*)&b[0] = *(const float4*)&Bs[kk][c0];
      *(float4*)&b[4] = *(const float4*)&Bs[kk][c0 + 4];
#pragma unroll
      for (int i = 0; i < 8; ++i)
#pragma unroll
        for (int j = 0; j < 8; ++j) acc[i][j] = fmaf(a[i], b[j], acc[i][j]);
    }
    __syncthreads();
  }
#pragma unroll
  for (int i = 0; i < 8; ++i) {
    float* crow = C + (size_t)(m0 + r0 + i) * DDIM + n0 + c0;
    float4 o0, o1;
    o0.x = acc[i][0] + bias[n0 + c0 + 0]; o0.y = acc[i][1] + bias[n0 + c0 + 1];
    o0.z = acc[i][2] + bias[n0 + c0 + 2]; o0.w = acc[i][3] + bias[n0 + c0 + 3];
    o1.x = acc[i][4] + bias[n0 + c0 + 4]; o1.y = acc[i][5] + bias[n0 + c0 + 5];
    o1.z = acc[i][6] + bias[n0 + c0 + 6]; o1.w = acc[i][7] + bias[n0 + c0 + 7];
    *(float4*)&crow[0] = o0; *(float4*)&crow[4] = o1;
  }
}

// h = relu(concat(filled) @ W1 + b1); A gathered from the 3 proj buffers.
__launch_bounds__(256)
__global__ void gemm_h1(const float* __restrict__ proj3, const float* __restrict__ Bw,
                        const float* __restrict__ bias, float* __restrict__ C) {
  const int K = 3072;
  __shared__ float As[BK][BM];
  __shared__ float Bs[BK][BN];
  const int t = threadIdx.x;
  const int n0 = blockIdx.x * BN, m0 = blockIdx.y * BM;
  const int tx = t & 15, ty = t >> 4;
  const int r0 = ty * 8, c0 = tx * 8;
  const int arow = t >> 1, akq = (t & 1) * 4;
  const int brow = t >> 5, bcol = (t & 31) * 4;
  float acc[8][8];
#pragma unroll
  for (int i = 0; i < 8; ++i)
#pragma unroll
    for (int j = 0; j < 8; ++j) acc[i][j] = 0.f;
  const float* Bptr = Bw + (size_t)brow * DDIM + n0 + bcol;
  for (int k0 = 0; k0 < K; k0 += BK) {
    const int kg = k0 + akq;  // float4 never crosses a 1024 boundary (kg % 4 == 0, k0 % 8 == 0)
    const float* Ab = proj3 + (size_t)(kg >> 10) * ((size_t)NB_ROWS * DDIM)
                    + (size_t)(m0 + arow) * DDIM + (kg & 1023);
    float4 av = *(const float4*)Ab;
    float4 bv = *(const float4*)(Bptr + (size_t)k0 * DDIM);
    As[akq + 0][arow] = av.x; As[akq + 1][arow] = av.y;
    As[akq + 2][arow] = av.z; As[akq + 3][arow] = av.w;
    *(float4*)&Bs[brow][bcol] = bv;
    __syncthreads();
#pragma unroll
    for (int kk = 0; kk < BK; ++kk) {
      float a[8], b[8];
      *(float4*)&a[0] = *(const float4*)&As[kk][r0];
      *(float4*)&a[4] = *(const float4*)&As[kk][r0 + 4];
      *(float4*)&b[0] = *(const float4*)&Bs[kk][c0];
      *(float4*)&b[4] = *(const float4*)&Bs[kk][c0 + 4];
#pragma unroll
      for (int i = 0; i < 8; ++i)
#pragma unroll
        for (int j = 0; j < 8; ++j) acc[i][j] = fmaf(a[i], b[j], acc[i][j]);
    }
    __syncthreads();
  }
#pragma unroll
  for (int i = 0; i < 8; ++i) {
    float* crow = C + (size_t)(m0 + r0 + i) * DDIM + n0 + c0;
    float4 o0, o1;
    o0.x = fmaxf(acc[i][0] + bias[n0 + c0 + 0], 0.f); o0.y = fmaxf(acc[i][1] + bias[n0 + c0 + 1], 0.f);
    o0.z = fmaxf(acc[i][2] + bias[n0 + c0 + 2], 0.f); o0.w = fmaxf(acc[i][3] + bias[n0 + c0 + 3], 0.f);
    o1.x = fmaxf(acc[i][4] + bias[n0 + c0 + 4], 0.f); o1.y = fmaxf(acc[i][5] + bias[n0 + c0 + 5], 0.f);
    o1.z = fmaxf(acc[i][6] + bias[n0 + c0 + 6], 0.f); o1.w = fmaxf(acc[i][7] + bias[n0 + c0 + 7], 0.f);
    *(float4*)&crow[0] = o0; *(float4*)&crow[4] = o1;
  }
}

// sim chunk: S[q - qoff, j] = bnk[qrows[q]] . bnk[j]  (both pre-normalized, NT GEMM)
__launch_bounds__(256)
__global__ void gemm_sim(const float* __restrict__ bnk, const int* __restrict__ qrw_m,
                         const int* __restrict__ meta, int mmod, int qoff,
                         float* __restrict__ S) {
  const int Nb = meta[2 * mmod], nQ = meta[2 * mmod + 1];
  const int n0 = blockIdx.x * BN, m0 = blockIdx.y * BM;
  if (qoff + m0 >= nQ || n0 >= Nb) return;   // uniform early exit
  __shared__ float As[BK][BM];
  __shared__ float Bs[BK][BN];
  const int t = threadIdx.x;
  const int tx = t & 15, ty = t >> 4;
  const int r0 = ty * 8, c0 = tx * 8;
  const int arow = t >> 1, akq = (t & 1) * 4;
  int qr = qoff + m0 + arow; if (qr > nQ - 1) qr = nQ - 1;  // clamp (rows >= nQ never written)
  const float* Aptr = bnk + (size_t)qrw_m[qr] * DDIM + akq;
  const float* Bptr = bnk + (size_t)(n0 + arow) * DDIM + akq;
  float acc[8][8];
#pragma unroll
  for (int i = 0; i < 8; ++i)
#pragma unroll
    for (int j = 0; j < 8; ++j) acc[i][j] = 0.f;
  for (int k0 = 0; k0 < DDIM; k0 += BK) {
    float4 av = *(const float4*)(Aptr + k0);
    float4 bv = *(const float4*)(Bptr + k0);
    As[akq + 0][arow] = av.x; As[akq + 1][arow] = av.y;
    As[akq + 2][arow] = av.z; As[akq + 3][arow] = av.w;
    Bs[akq + 0][arow] = bv.x; Bs[akq + 1][arow] = bv.y;
    Bs[akq + 2][arow] = bv.z; Bs[akq + 3][arow] = bv.w;
    __syncthreads();
#pragma unroll
    for (int kk = 0; kk < BK; ++kk) {
      float a[8], b[8];
      *(float4*)&a[0] = *(const float4*)&As[kk][r0];
      *(float4*)&a[4] = *(const float4*)&As[kk][r0 + 4];
      *(float4*)&b[0] = *(const float4*)&Bs[kk][c0];
      *(float4*)&b[4] = *(const float4*)&Bs[kk][c0 + 4];
#pragma unroll
      for (int i = 0; i < 8; ++i)
#pragma unroll
        for (int j = 0; j < 8; ++j) acc[i][j] = fmaf(a[i], b[j], acc[i][j]);
    }
    __syncthreads();
  }
#pragma unroll
  for (int i = 0; i < 8; ++i) {
    const int gr = qoff + m0 + r0 + i;
    if (gr < nQ) {
      float* crow = S + (size_t)(m0 + r0 + i) * NB_ROWS + n0 + c0;
      float4 o0, o1;
      o0.x = acc[i][0]; o0.y = acc[i][1]; o0.z = acc[i][2]; o0.w = acc[i][3];
      o1.x = acc[i][4]; o1.y = acc[i][5]; o1.z = acc[i][6]; o1.w = acc[i][7];
      *(float4*)&crow[0] = o0; *(float4*)&crow[4] = o1;
    }
  }
}

// ---------------- norms, bank build, fill, tail-zero, final ----------------
__global__ void norms_kernel(const float* __restrict__ proj3, float* __restrict__ norms) {
  const int row = blockIdx.x, m = blockIdx.y, t = threadIdx.x;
  const float* p = proj3 + ((size_t)m * NB_ROWS + row) * DDIM;
  float4 v = *(const float4*)&p[t * 4];
  float s = v.x * v.x + v.y * v.y + v.z * v.z + v.w * v.w;
  for (int o = 32; o > 0; o >>= 1) s += __shfl_down(s, o, 64);
  __shared__ float ls[4];
  if ((t & 63) == 0) ls[t >> 6] = s;
  __syncthreads();
  if (t == 0) norms[m * NB_ROWS + row] = fmaxf(sqrtf(ls[0] + ls[1] + ls[2] + ls[3]), 1e-8f);
}

__global__ void build_bnk(const float* __restrict__ projm, const float* __restrict__ normsm,
                          const int* __restrict__ b2bm, const int* __restrict__ meta,
                          int mmod, float* __restrict__ bnk) {
  const int j = blockIdx.x, t = threadIdx.x;
  const int Nb = meta[2 * mmod];
  float4 o;
  if (j < Nb) {
    const int b = b2bm[j];
    const float nrm = normsm[b];
    float4 v = *(const float4*)(projm + (size_t)b * DDIM + t * 4);
    o.x = v.x / nrm; o.y = v.y / nrm; o.z = v.z / nrm; o.w = v.w / nrm;
  } else {
    o.x = o.y = o.z = o.w = 0.f;
  }
  *(float4*)(bnk + (size_t)j * DDIM + t * 4) = o;
}

__global__ void topk_fill(const float* __restrict__ S, float* __restrict__ projm,
                          const int* __restrict__ b2bm, const int* __restrict__ qrw_m,
                          const int* __restrict__ meta, const int* __restrict__ miss,
                          int mmod, int qoff) {
  const int Nb = meta[2 * mmod], nQ = meta[2 * mmod + 1];
  const int q = qoff + blockIdx.x;
  if (q >= nQ) return;
  const int t = threadIdx.x, tmod = mmod + 1;
  const float* srow = S + (size_t)blockIdx.x * NB_ROWS;
  float v0 = -INFINITY, v1 = -INFINITY, v2 = -INFINITY;
  int i0 = 0x7fffffff, i1 = 0x7fffffff, i2 = 0x7fffffff;
  for (int j = t; j < Nb; j += 256) {
    if (miss[j] == tmod) continue;          // col_valid = avail[j] && j < Nb
    const float s = srow[j];
    if (pair_better(s, j, v0, i0)) { v2 = v1; i2 = i1; v1 = v0; i1 = i0; v0 = s; i0 = j; }
    else if (pair_better(s, j, v1, i1)) { v2 = v1; i2 = i1; v1 = s; i1 = j; }
    else if (pair_better(s, j, v2, i2)) { v2 = s; i2 = j; }
  }
  __shared__ float sv[768];
  __shared__ int si[768];
  sv[t * 3 + 0] = v0; sv[t * 3 + 1] = v1; sv[t * 3 + 2] = v2;
  si[t * 3 + 0] = i0; si[t * 3 + 1] = i1; si[t * 3 + 2] = i2;
  __syncthreads();
  __shared__ float wsh[3];
  __shared__ int idsh[3];
  if (t == 0) {
    float c0 = -INFINITY, c1 = -INFINITY, c2 = -INFINITY;
    int j0 = 0x7fffffff, j1 = 0x7fffffff, j2 = 0x7fffffff;
    for (int e = 0; e < 768; ++e) {
      const float s = sv[e]; const int j = si[e];
      if (pair_better(s, j, c0, j0)) { c2 = c1; j2 = j1; c1 = c0; j1 = j0; c0 = s; j0 = j; }
      else if (pair_better(s, j, c1, j1)) { c2 = c1; j2 = j1; c1 = s; j1 = j; }
      else if (pair_better(s, j, c2, j2)) { c2 = s; j2 = j; }
    }
    if (c0 == -INFINITY) {                   // no valid candidate anywhere -> knn = 0
      wsh[0] = wsh[1] = wsh[2] = 0.f; idsh[0] = idsh[1] = idsh[2] = 0;
    } else {
      const float e1 = (c1 == -INFINITY) ? 0.f : expf(c1 - c0);
      const float e2 = (c2 == -INFINITY) ? 0.f : expf(c2 - c0);
      const float inv = 1.f / (1.f + e1 + e2);
      wsh[0] = inv; wsh[1] = e1 * inv; wsh[2] = e2 * inv;
      idsh[0] = j0; idsh[1] = (c1 == -INFINITY) ? j0 : j1; idsh[2] = (c2 == -INFINITY) ? j0 : j2;
    }
  }
  __syncthreads();
  const float w0 = wsh[0], w1 = wsh[1], w2 = wsh[2];
  // gather unnormalized bank rows (avail rows — never overwritten by fills)
  const float* p0 = projm + (size_t)b2bm[idsh[0]] * DDIM;
  const float* p1 = projm + (size_t)b2bm[idsh[1]] * DDIM;
  const float* p2 = projm + (size_t)b2bm[idsh[2]] * DDIM;
  const int qrow = qrw_m[q];                 // missing row — safe to overwrite
  const int e = t * 4;
  float4 a = *(const float4*)(p0 + e);
  float4 b = *(const float4*)(p1 + e);
  float4 c = *(const float4*)(p2 + e);
  float4 o;
  o.x = w0 * a.x + w1 * b.x + w2 * c.x;
  o.y = w0 * a.y + w1 * b.y + w2 * c.y;
  o.z = w0 * a.z + w1 * b.z + w2 * c.z;
  o.w = w0 * a.w + w1 * b.w + w2 * c.w;
  *(float4*)(projm + (size_t)qrow * DDIM + e) = o;
}

__global__ void zero_tail(const int* __restrict__ miss, const int* __restrict__ meta,
                          float* __restrict__ proj3) {
  const int row = blockIdx.x, m = blockIdx.y;
  if (miss[row] != m + 1) return;
  if (row < meta[2 * m]) return;             // only missing rows with idx >= Nb -> 0
  float4 z; z.x = z.y = z.z = z.w = 0.f;
  *(float4*)(proj3 + ((size_t)m * NB_ROWS + row) * DDIM + threadIdx.x * 4) = z;
}

__global__ void out_kernel(const float* __restrict__ h1, const float* __restrict__ w2,
                           const float* __restrict__ b2p, float* __restrict__ out) {
  const int row = blockIdx.x, t = threadIdx.x;
  float4 h = *(const float4*)(h1 + (size_t)row * DDIM + t * 4);
  float4 w = *(const float4*)(w2 + t * 4);
  float s = h.x * w.x + h.y * w.y + h.z * w.z + h.w * w.w;
  for (int o = 32; o > 0; o >>= 1) s += __shfl_down(s, o, 64);
  __shared__ float ls[4];
  if ((t & 63) == 0) ls[t >> 6] = s;
  __syncthreads();
  if (t == 0) out[row] = ls[0] + ls[1] + ls[2] + ls[3] + b2p[0];
}

extern "C" void kernel_launch(void* const* d_in, const int* in_sizes, int n_in,
                              void* d_out, int out_size, void* d_ws, size_t ws_size,
                              hipStream_t stream) {
  const float* xs[3] = {(const float*)d_in[0], (const float*)d_in[1], (const float*)d_in[2]};
  const int* miss = (const int*)d_in[3];
  const float* Wm[3] = {(const float*)d_in[4], (const float*)d_in[6], (const float*)d_in[8]};
  const float* bm[3] = {(const float*)d_in[5], (const float*)d_in[7], (const float*)d_in[9]};
  const float* W1 = (const float*)d_in[10];
  const float* b1 = (const float*)d_in[11];
  const float* W2 = (const float*)d_in[12];
  const float* b2v = (const float*)d_in[13];

  char* base = (char*)d_ws;
  size_t off = 0;
  auto carve = [&](size_t bytes) -> void* {
    void* p = base + off;
    off += (bytes + 255) & ~(size_t)255;
    return p;
  };
  int*   meta  = (int*)carve(64);
  int*   b2b   = (int*)carve((size_t)3 * NB_ROWS * sizeof(int));
  int*   qrw   = (int*)carve((size_t)3 * 4096 * sizeof(int));
  float* norms = (float*)carve((size_t)3 * NB_ROWS * sizeof(float));
  float* proj  = (float*)carve((size_t)3 * NB_ROWS * DDIM * sizeof(float));  // becomes `filled`
  float* bnk   = (float*)carve((size_t)NB_ROWS * DDIM * sizeof(float));
  float* sim   = (float*)carve((size_t)1024 * NB_ROWS * sizeof(float));
  float* h1    = (float*)carve((size_t)NB_ROWS * DDIM * sizeof(float));
  if (off > ws_size) return;  // ~160.5 MB needed

  scan_kernel<<<dim3(3), dim3(256), 0, stream>>>(miss, meta, b2b, qrw);

  for (int m = 0; m < 3; ++m)
    gemm_proj<<<dim3(8, 64), dim3(256), 0, stream>>>(
        xs[m], Wm[m], bm[m], proj + (size_t)m * NB_ROWS * DDIM, 2048);

  norms_kernel<<<dim3(NB_ROWS, 3), dim3(256), 0, stream>>>(proj, norms);

  for (int m = 0; m < 3; ++m) {
    build_bnk<<<dim3(NB_ROWS), dim3(256), 0, stream>>>(
        proj + (size_t)m * NB_ROWS * DDIM, norms + m * NB_ROWS, b2b + m * NB_ROWS, meta, m, bnk);
    for (int c = 0; c < 4; ++c) {  // up to 4096 query rows, chunks of 1024
      gemm_sim<<<dim3(64, 8), dim3(256), 0, stream>>>(bnk, qrw + m * 4096, meta, m, c * 1024, sim);
      topk_fill<<<dim3(1024), dim3(256), 0, stream>>>(
          sim, proj + (size_t)m * NB_ROWS * DDIM, b2b + m * NB_ROWS, qrw + m * 4096,
          meta, miss, m, c * 1024);
    }
  }

  zero_tail<<<dim3(NB_ROWS, 3), dim3(256), 0, stream>>>(miss, meta, proj);
  gemm_h1<<<dim3(8, 64), dim3(256), 0, stream>>>(proj, W1, b1, h1);
  out_kernel<<<dim3(NB_ROWS), dim3(256), 0, stream>>>(h1, W2, b2v, (float*)d_out);
}

// Round 2
// 2557.276 us; speedup vs baseline: 1.7004x; 1.7004x over previous
//
#include <hip/hip_runtime.h>
#include <math.h>

#define NB_ROWS 8192
#define DDIM 1024

typedef _Float16 f16x8 __attribute__((ext_vector_type(8)));
typedef _Float16 f16x4 __attribute__((ext_vector_type(4)));
typedef float f32x4 __attribute__((ext_vector_type(4)));

#define LO_SCALE 1024.0f
#define LO_INV (1.0f / 1024.0f)

__device__ __forceinline__ void gload_lds16(const void* g, void* l) {
  __builtin_amdgcn_global_load_lds((const __attribute__((address_space(1))) void*)g,
                                   (__attribute__((address_space(3))) void*)l, 16, 0, 0);
}

__device__ __forceinline__ bool pair_better(float s, int j, float v, int i) {
  return (s > v) || (s == v && j < i);
}

__device__ __forceinline__ f16x8 cvt_hi8(float4 a, float4 b) {
  f16x8 r;
  r[0] = (_Float16)a.x; r[1] = (_Float16)a.y; r[2] = (_Float16)a.z; r[3] = (_Float16)a.w;
  r[4] = (_Float16)b.x; r[5] = (_Float16)b.y; r[6] = (_Float16)b.z; r[7] = (_Float16)b.w;
  return r;
}
__device__ __forceinline__ f16x8 cvt_lo8(float4 a, float4 b, f16x8 h) {
  f16x8 r;
  r[0] = (_Float16)((a.x - (float)h[0]) * LO_SCALE);
  r[1] = (_Float16)((a.y - (float)h[1]) * LO_SCALE);
  r[2] = (_Float16)((a.z - (float)h[2]) * LO_SCALE);
  r[3] = (_Float16)((a.w - (float)h[3]) * LO_SCALE);
  r[4] = (_Float16)((b.x - (float)h[4]) * LO_SCALE);
  r[5] = (_Float16)((b.y - (float)h[5]) * LO_SCALE);
  r[6] = (_Float16)((b.z - (float)h[6]) * LO_SCALE);
  r[7] = (_Float16)((b.w - (float)h[7]) * LO_SCALE);
  return r;
}

// ---------------- scan: bank2batch + query list per modality ----------------
__global__ void scan_kernel(const int* __restrict__ miss, int* __restrict__ meta,
                            int* __restrict__ b2b, int* __restrict__ qrw) {
  const int m = blockIdx.x, t = threadIdx.x, tmod = m + 1;
  __shared__ int cnt[256];
  const int base = t * 32;
  int c = 0;
  for (int i = 0; i < 32; ++i) c += (miss[base + i] != tmod) ? 1 : 0;
  cnt[t] = c; __syncthreads();
  for (int s = 1; s < 256; s <<= 1) {
    int v = (t >= s) ? cnt[t - s] : 0;
    __syncthreads();
    cnt[t] += v;
    __syncthreads();
  }
  const int Nb = cnt[255];
  int pos = cnt[t] - c;
  for (int i = 0; i < 32; ++i) {
    int r = base + i;
    if (miss[r] != tmod) b2b[m * NB_ROWS + (pos++)] = r;
  }
  __syncthreads();
  int q = 0;
  for (int i = 0; i < 32; ++i) {
    int r = base + i;
    q += (miss[r] == tmod && r < Nb) ? 1 : 0;
  }
  cnt[t] = q; __syncthreads();
  for (int s = 1; s < 256; s <<= 1) {
    int v = (t >= s) ? cnt[t - s] : 0;
    __syncthreads();
    cnt[t] += v;
    __syncthreads();
  }
  const int nQ = cnt[255];
  int qpos = cnt[t] - q;
  for (int i = 0; i < 32; ++i) {
    int r = base + i;
    if (miss[r] == tmod && r < Nb) qrw[m * 4096 + (qpos++)] = r;
  }
  for (int i = nQ + t; i < 4096; i += 256) qrw[m * 4096 + i] = 0;  // pad tail
  if (t == 0) { meta[2 * m] = Nb; meta[2 * m + 1] = nQ; }
}

// ------------- transpose + fp16 split: W[K][N] -> Th/Tl[N][K] ---------------
__global__ void tsplit(const float* __restrict__ W, _Float16* __restrict__ Th,
                       _Float16* __restrict__ Tl, int K, int N) {
  __shared__ float tile[32][33];
  const int k0 = blockIdx.x * 32, n0 = blockIdx.y * 32;
  const int tx = threadIdx.x, ty = threadIdx.y;
  for (int i = ty; i < 32; i += 8)
    tile[i][tx] = W[(size_t)(k0 + i) * N + n0 + tx];
  __syncthreads();
  for (int i = ty; i < 32; i += 8) {
    float v = tile[tx][i];
    _Float16 h = (_Float16)v;
    Th[(size_t)(n0 + i) * K + k0 + tx] = h;
    if (Tl) Tl[(size_t)(n0 + i) * K + k0 + tx] = (_Float16)((v - (float)h) * LO_SCALE);
  }
}

// ---- MFMA split GEMM: C[M,1024] = A_f32[M,K] @ Bt(hi/lo)[1024,K]^T + bias ----
// 128x128 tile, BK=32 (rows: 8 chunks of 8 halves = [hi0..3 | lo0..3], XOR-(r&7) swizzle)
__launch_bounds__(256)
__global__ void gemm_proj_mfma(const float* __restrict__ A,
                               const _Float16* __restrict__ Bth,
                               const _Float16* __restrict__ Btl,
                               const float* __restrict__ bias,
                               float* __restrict__ C, int K) {
  __shared__ __align__(16) _Float16 Abuf[128 * 64];
  __shared__ __align__(16) _Float16 Bbuf[128 * 64];
  const int t = threadIdx.x;
  const int w = t >> 6, ln = t & 63;
  const int n0 = blockIdx.x * 128, m0 = blockIdx.y * 128;
  const int moff = (w & 1) * 64, noff = (w >> 1) * 64;
  const int lq = ln >> 4, lr = ln & 15;

  const int ar = t >> 1, ah = t & 1;
  const float* Ag = A + (size_t)(m0 + ar) * K + ah * 16;
  _Float16* AwrBase = &Abuf[ar * 64];
  const int ac0 = ah * 2;

  const _Float16* bsrc[4];
  _Float16* bdst[4];
#pragma unroll
  for (int p = 0; p < 4; ++p) {
    int r = p * 32 + w * 8 + (ln >> 3);
    int l = (ln & 7) ^ (r & 7);
    bsrc[p] = (l < 4) ? (Bth + (size_t)(n0 + r) * K + l * 8)
                      : (Btl + (size_t)(n0 + r) * K + (l - 4) * 8);
    bdst[p] = &Bbuf[(p * 32 + w * 8) * 64];
  }

  f32x4 acc[4][4] = {};
  f32x4 acc2[4][4] = {};

  for (int k0 = 0; k0 < K; k0 += 32) {
#pragma unroll
    for (int p = 0; p < 4; ++p) gload_lds16(bsrc[p] + k0, bdst[p]);
    float4 f0 = *(const float4*)(Ag + k0);
    float4 f1 = *(const float4*)(Ag + k0 + 4);
    float4 f2 = *(const float4*)(Ag + k0 + 8);
    float4 f3 = *(const float4*)(Ag + k0 + 12);
    f16x8 hi0 = cvt_hi8(f0, f1), hi1 = cvt_hi8(f2, f3);
    f16x8 lo0 = cvt_lo8(f0, f1, hi0), lo1 = cvt_lo8(f2, f3, hi1);
    *(f16x8*)&AwrBase[((ac0) ^ (ar & 7)) * 8] = hi0;
    *(f16x8*)&AwrBase[((ac0 + 1) ^ (ar & 7)) * 8] = hi1;
    *(f16x8*)&AwrBase[((ac0 + 4) ^ (ar & 7)) * 8] = lo0;
    *(f16x8*)&AwrBase[((ac0 + 5) ^ (ar & 7)) * 8] = lo1;
    __syncthreads();
    f16x8 ahi[4], alo[4];
#pragma unroll
    for (int mt = 0; mt < 4; ++mt) {
      int r = moff + mt * 16 + lr;
      ahi[mt] = *(f16x8*)&Abuf[r * 64 + ((lq) ^ (r & 7)) * 8];
      alo[mt] = *(f16x8*)&Abuf[r * 64 + ((lq + 4) ^ (r & 7)) * 8];
    }
#pragma unroll
    for (int nt = 0; nt < 4; ++nt) {
      int r = noff + nt * 16 + lr;
      f16x8 bhi = *(f16x8*)&Bbuf[r * 64 + ((lq) ^ (r & 7)) * 8];
      f16x8 blo = *(f16x8*)&Bbuf[r * 64 + ((lq + 4) ^ (r & 7)) * 8];
#pragma unroll
      for (int mt = 0; mt < 4; ++mt) {
        acc[mt][nt]  = __builtin_amdgcn_mfma_f32_16x16x32_f16(ahi[mt], bhi, acc[mt][nt], 0, 0, 0);
        acc2[mt][nt] = __builtin_amdgcn_mfma_f32_16x16x32_f16(ahi[mt], blo, acc2[mt][nt], 0, 0, 0);
        acc2[mt][nt] = __builtin_amdgcn_mfma_f32_16x16x32_f16(alo[mt], bhi, acc2[mt][nt], 0, 0, 0);
      }
    }
    __syncthreads();
  }
#pragma unroll
  for (int nt = 0; nt < 4; ++nt) {
    int col = n0 + noff + nt * 16 + lr;
    float bv = bias[col];
#pragma unroll
    for (int mt = 0; mt < 4; ++mt) {
      int row = m0 + moff + mt * 16 + lq * 4;
#pragma unroll
      for (int r = 0; r < 4; ++r)
        C[(size_t)(row + r) * DDIM + col] = acc[mt][nt][r] + acc2[mt][nt][r] * LO_INV + bv;
    }
  }
}

// ---- MFMA split sim: S[q-qoff, j] = Aq(hi/lo gathered) . bank(hi/lo) -------
__launch_bounds__(256)
__global__ void gemm_sim_mfma(const _Float16* __restrict__ bh, const _Float16* __restrict__ bl,
                              const int* __restrict__ qrw_m, const int* __restrict__ meta,
                              int mmod, int qoff, float* __restrict__ S) {
  const int Nb = meta[2 * mmod], nQ = meta[2 * mmod + 1];
  const int n0 = blockIdx.x * 128, m0 = blockIdx.y * 128;
  if (qoff + m0 >= nQ || n0 >= Nb) return;
  __shared__ __align__(16) _Float16 Abuf[128 * 64];
  __shared__ __align__(16) _Float16 Bbuf[128 * 64];
  const int t = threadIdx.x;
  const int w = t >> 6, ln = t & 63;
  const int moff = (w & 1) * 64, noff = (w >> 1) * 64;
  const int lq = ln >> 4, lr = ln & 15;

  const _Float16* asrc[4];
  const _Float16* bsrc[4];
  _Float16* adst[4];
  _Float16* bdst[4];
#pragma unroll
  for (int p = 0; p < 4; ++p) {
    int r = p * 32 + w * 8 + (ln >> 3);
    int l = (ln & 7) ^ (r & 7);
    int q = qoff + m0 + r; if (q > 4095) q = 4095;
    int arow = qrw_m[q];
    asrc[p] = (l < 4) ? (bh + (size_t)arow * DDIM + l * 8)
                      : (bl + (size_t)arow * DDIM + (l - 4) * 8);
    bsrc[p] = (l < 4) ? (bh + (size_t)(n0 + r) * DDIM + l * 8)
                      : (bl + (size_t)(n0 + r) * DDIM + (l - 4) * 8);
    adst[p] = &Abuf[(p * 32 + w * 8) * 64];
    bdst[p] = &Bbuf[(p * 32 + w * 8) * 64];
  }

  f32x4 acc[4][4] = {};
  f32x4 acc2[4][4] = {};

  for (int k0 = 0; k0 < DDIM; k0 += 32) {
#pragma unroll
    for (int p = 0; p < 4; ++p) {
      gload_lds16(asrc[p] + k0, adst[p]);
      gload_lds16(bsrc[p] + k0, bdst[p]);
    }
    __syncthreads();
    f16x8 ahi[4], alo[4];
#pragma unroll
    for (int mt = 0; mt < 4; ++mt) {
      int r = moff + mt * 16 + lr;
      ahi[mt] = *(f16x8*)&Abuf[r * 64 + ((lq) ^ (r & 7)) * 8];
      alo[mt] = *(f16x8*)&Abuf[r * 64 + ((lq + 4) ^ (r & 7)) * 8];
    }
#pragma unroll
    for (int nt = 0; nt < 4; ++nt) {
      int r = noff + nt * 16 + lr;
      f16x8 bhi = *(f16x8*)&Bbuf[r * 64 + ((lq) ^ (r & 7)) * 8];
      f16x8 blo = *(f16x8*)&Bbuf[r * 64 + ((lq + 4) ^ (r & 7)) * 8];
#pragma unroll
      for (int mt = 0; mt < 4; ++mt) {
        acc[mt][nt]  = __builtin_amdgcn_mfma_f32_16x16x32_f16(ahi[mt], bhi, acc[mt][nt], 0, 0, 0);
        acc2[mt][nt] = __builtin_amdgcn_mfma_f32_16x16x32_f16(ahi[mt], blo, acc2[mt][nt], 0, 0, 0);
        acc2[mt][nt] = __builtin_amdgcn_mfma_f32_16x16x32_f16(alo[mt], bhi, acc2[mt][nt], 0, 0, 0);
      }
    }
    __syncthreads();
  }
#pragma unroll
  for (int nt = 0; nt < 4; ++nt) {
    int col = n0 + noff + nt * 16 + lr;
#pragma unroll
    for (int mt = 0; mt < 4; ++mt) {
      int lrow = m0 + moff + mt * 16 + lq * 4;
#pragma unroll
      for (int r = 0; r < 4; ++r) {
        if (qoff + lrow + r < nQ)
          S[(size_t)(lrow + r) * NB_ROWS + col] = acc[mt][nt][r] + acc2[mt][nt][r] * LO_INV;
      }
    }
  }
}

// ---- MFMA plain fp16 GEMM: H = relu(concat(proj3) @ W1 + b1), fp16 out -----
// BK=64 (rows: 8 chunks of 8 halves = k 0..63, XOR swizzle)
__launch_bounds__(256)
__global__ void gemm_h1_mfma(const float* __restrict__ proj3, const _Float16* __restrict__ W1t,
                             const float* __restrict__ bias, _Float16* __restrict__ H) {
  const int K = 3072;
  __shared__ __align__(16) _Float16 Abuf[128 * 64];
  __shared__ __align__(16) _Float16 Bbuf[128 * 64];
  const int t = threadIdx.x;
  const int w = t >> 6, ln = t & 63;
  const int n0 = blockIdx.x * 128, m0 = blockIdx.y * 128;
  const int moff = (w & 1) * 64, noff = (w >> 1) * 64;
  const int lq = ln >> 4, lr = ln & 15;

  const int ar = t >> 1, ah = t & 1;
  _Float16* AwrBase = &Abuf[ar * 64];

  const _Float16* bsrc[4];
  _Float16* bdst[4];
#pragma unroll
  for (int p = 0; p < 4; ++p) {
    int r = p * 32 + w * 8 + (ln >> 3);
    int l = (ln & 7) ^ (r & 7);
    bsrc[p] = W1t + (size_t)(n0 + r) * K + l * 8;
    bdst[p] = &Bbuf[(p * 32 + w * 8) * 64];
  }

  f32x4 acc[4][4] = {};

  for (int k0 = 0; k0 < K; k0 += 64) {
#pragma unroll
    for (int p = 0; p < 4; ++p) gload_lds16(bsrc[p] + k0, bdst[p]);
#pragma unroll
    for (int j = 0; j < 4; ++j) {
      const int c = ah * 4 + j;
      const int kg = k0 + c * 8;
      const int mi = kg >> 10, colk = kg & 1023;
      const float* src = proj3 + (size_t)mi * (NB_ROWS * DDIM) + (size_t)(m0 + ar) * DDIM + colk;
      float4 f0 = *(const float4*)(src);
      float4 f1 = *(const float4*)(src + 4);
      *(f16x8*)&AwrBase[((c) ^ (ar & 7)) * 8] = cvt_hi8(f0, f1);
    }
    __syncthreads();
#pragma unroll
    for (int ks = 0; ks < 2; ++ks) {
      f16x8 a[4];
#pragma unroll
      for (int mt = 0; mt < 4; ++mt) {
        int r = moff + mt * 16 + lr;
        a[mt] = *(f16x8*)&Abuf[r * 64 + ((ks * 4 + lq) ^ (r & 7)) * 8];
      }
#pragma unroll
      for (int nt = 0; nt < 4; ++nt) {
        int r = noff + nt * 16 + lr;
        f16x8 b = *(f16x8*)&Bbuf[r * 64 + ((ks * 4 + lq) ^ (r & 7)) * 8];
#pragma unroll
        for (int mt = 0; mt < 4; ++mt)
          acc[mt][nt] = __builtin_amdgcn_mfma_f32_16x16x32_f16(a[mt], b, acc[mt][nt], 0, 0, 0);
      }
    }
    __syncthreads();
  }
#pragma unroll
  for (int nt = 0; nt < 4; ++nt) {
    int col = n0 + noff + nt * 16 + lr;
    float bv = bias[col];
#pragma unroll
    for (int mt = 0; mt < 4; ++mt) {
      int row = m0 + moff + mt * 16 + lq * 4;
#pragma unroll
      for (int r = 0; r < 4; ++r)
        H[(size_t)(row + r) * DDIM + col] = (_Float16)fmaxf(acc[mt][nt][r] + bv, 0.f);
    }
  }
}

// ---------------- norms, bank build, fill, tail-zero, final ----------------
__global__ void norms_kernel(const float* __restrict__ proj3, float* __restrict__ norms) {
  const int row = blockIdx.x, m = blockIdx.y, t = threadIdx.x;
  const float* p = proj3 + ((size_t)m * NB_ROWS + row) * DDIM;
  float4 v = *(const float4*)&p[t * 4];
  float s = v.x * v.x + v.y * v.y + v.z * v.z + v.w * v.w;
  for (int o = 32; o > 0; o >>= 1) s += __shfl_down(s, o, 64);
  __shared__ float ls[4];
  if ((t & 63) == 0) ls[t >> 6] = s;
  __syncthreads();
  if (t == 0) norms[m * NB_ROWS + row] = fmaxf(sqrtf(ls[0] + ls[1] + ls[2] + ls[3]), 1e-8f);
}

__global__ void build_bnk(const float* __restrict__ projm, const float* __restrict__ normsm,
                          const int* __restrict__ b2bm, const int* __restrict__ meta,
                          int mmod, _Float16* __restrict__ bnh, _Float16* __restrict__ bnl) {
  const int j = blockIdx.x, t = threadIdx.x;
  const int Nb = meta[2 * mmod];
  f16x4 hv, lv;
  if (j < Nb) {
    const int b = b2bm[j];
    const float inv = 1.0f / normsm[b];
    float4 v = *(const float4*)(projm + (size_t)b * DDIM + t * 4);
    float bn0 = v.x * inv, bn1 = v.y * inv, bn2 = v.z * inv, bn3 = v.w * inv;
    hv[0] = (_Float16)bn0; hv[1] = (_Float16)bn1; hv[2] = (_Float16)bn2; hv[3] = (_Float16)bn3;
    lv[0] = (_Float16)((bn0 - (float)hv[0]) * LO_SCALE);
    lv[1] = (_Float16)((bn1 - (float)hv[1]) * LO_SCALE);
    lv[2] = (_Float16)((bn2 - (float)hv[2]) * LO_SCALE);
    lv[3] = (_Float16)((bn3 - (float)hv[3]) * LO_SCALE);
  } else {
    hv = (f16x4)0; lv = (f16x4)0;
  }
  *(f16x4*)&bnh[(size_t)j * DDIM + t * 4] = hv;
  *(f16x4*)&bnl[(size_t)j * DDIM + t * 4] = lv;
}

__global__ void topk_fill(const float* __restrict__ S, float* __restrict__ projm,
                          const int* __restrict__ b2bm, const int* __restrict__ qrw_m,
                          const int* __restrict__ meta, const int* __restrict__ miss,
                          int mmod, int qoff) {
  const int Nb = meta[2 * mmod], nQ = meta[2 * mmod + 1];
  const int q = qoff + blockIdx.x;
  if (q >= nQ) return;
  const int t = threadIdx.x, tmod = mmod + 1;
  const float* srow = S + (size_t)blockIdx.x * NB_ROWS;
  float v0 = -INFINITY, v1 = -INFINITY, v2 = -INFINITY;
  int i0 = 0x7fffffff, i1 = 0x7fffffff, i2 = 0x7fffffff;
  for (int j = t; j < Nb; j += 256) {
    if (miss[j] == tmod) continue;
    const float s = srow[j];
    if (pair_better(s, j, v0, i0)) { v2 = v1; i2 = i1; v1 = v0; i1 = i0; v0 = s; i0 = j; }
    else if (pair_better(s, j, v1, i1)) { v2 = v1; i2 = i1; v1 = s; i1 = j; }
    else if (pair_better(s, j, v2, i2)) { v2 = s; i2 = j; }
  }
  __shared__ float sv[768];
  __shared__ int si[768];
  sv[t * 3 + 0] = v0; sv[t * 3 + 1] = v1; sv[t * 3 + 2] = v2;
  si[t * 3 + 0] = i0; si[t * 3 + 1] = i1; si[t * 3 + 2] = i2;
  __syncthreads();
  __shared__ float wsh[3];
  __shared__ int idsh[3];
  if (t == 0) {
    float c0 = -INFINITY, c1 = -INFINITY, c2 = -INFINITY;
    int j0 = 0x7fffffff, j1 = 0x7fffffff, j2 = 0x7fffffff;
    for (int e = 0; e < 768; ++e) {
      const float s = sv[e]; const int j = si[e];
      if (pair_better(s, j, c0, j0)) { c2 = c1; j2 = j1; c1 = c0; j1 = j0; c0 = s; j0 = j; }
      else if (pair_better(s, j, c1, j1)) { c2 = c1; j2 = j1; c1 = s; j1 = j; }
      else if (pair_better(s, j, c2, j2)) { c2 = s; j2 = j; }
    }
    if (c0 == -INFINITY) {
      wsh[0] = wsh[1] = wsh[2] = 0.f; idsh[0] = idsh[1] = idsh[2] = 0;
    } else {
      const float e1 = (c1 == -INFINITY) ? 0.f : expf(c1 - c0);
      const float e2 = (c2 == -INFINITY) ? 0.f : expf(c2 - c0);
      const float inv = 1.f / (1.f + e1 + e2);
      wsh[0] = inv; wsh[1] = e1 * inv; wsh[2] = e2 * inv;
      idsh[0] = j0; idsh[1] = (c1 == -INFINITY) ? j0 : j1; idsh[2] = (c2 == -INFINITY) ? j0 : j2;
    }
  }
  __syncthreads();
  const float w0 = wsh[0], w1 = wsh[1], w2 = wsh[2];
  const float* p0 = projm + (size_t)b2bm[idsh[0]] * DDIM;
  const float* p1 = projm + (size_t)b2bm[idsh[1]] * DDIM;
  const float* p2 = projm + (size_t)b2bm[idsh[2]] * DDIM;
  const int qrow = qrw_m[q];
  const int e = t * 4;
  float4 a = *(const float4*)(p0 + e);
  float4 b = *(const float4*)(p1 + e);
  float4 c = *(const float4*)(p2 + e);
  float4 o;
  o.x = w0 * a.x + w1 * b.x + w2 * c.x;
  o.y = w0 * a.y + w1 * b.y + w2 * c.y;
  o.z = w0 * a.z + w1 * b.z + w2 * c.z;
  o.w = w0 * a.w + w1 * b.w + w2 * c.w;
  *(float4*)(projm + (size_t)qrow * DDIM + e) = o;
}

__global__ void zero_tail(const int* __restrict__ miss, const int* __restrict__ meta,
                          float* __restrict__ proj3) {
  const int row = blockIdx.x, m = blockIdx.y;
  if (miss[row] != m + 1) return;
  if (row < meta[2 * m]) return;
  float4 z; z.x = z.y = z.z = z.w = 0.f;
  *(float4*)(proj3 + ((size_t)m * NB_ROWS + row) * DDIM + threadIdx.x * 4) = z;
}

__global__ void out_kernel(const _Float16* __restrict__ h1, const float* __restrict__ w2,
                           const float* __restrict__ b2p, float* __restrict__ out) {
  const int row = blockIdx.x, t = threadIdx.x;
  f16x4 h = *(const f16x4*)&h1[(size_t)row * DDIM + t * 4];
  float4 w = *(const float4*)&w2[t * 4];
  float s = (float)h[0] * w.x + (float)h[1] * w.y + (float)h[2] * w.z + (float)h[3] * w.w;
  for (int o = 32; o > 0; o >>= 1) s += __shfl_down(s, o, 64);
  __shared__ float ls[4];
  if ((t & 63) == 0) ls[t >> 6] = s;
  __syncthreads();
  if (t == 0) out[row] = ls[0] + ls[1] + ls[2] + ls[3] + b2p[0];
}

extern "C" void kernel_launch(void* const* d_in, const int* in_sizes, int n_in,
                              void* d_out, int out_size, void* d_ws, size_t ws_size,
                              hipStream_t stream) {
  const float* xs[3] = {(const float*)d_in[0], (const float*)d_in[1], (const float*)d_in[2]};
  const int* miss = (const int*)d_in[3];
  const float* Wm[3] = {(const float*)d_in[4], (const float*)d_in[6], (const float*)d_in[8]};
  const float* bm[3] = {(const float*)d_in[5], (const float*)d_in[7], (const float*)d_in[9]};
  const float* W1 = (const float*)d_in[10];
  const float* b1 = (const float*)d_in[11];
  const float* W2 = (const float*)d_in[12];
  const float* b2v = (const float*)d_in[13];

  char* base = (char*)d_ws;
  size_t off = 0;
  auto carve = [&](size_t bytes) -> void* {
    void* p = base + off;
    off += (bytes + 255) & ~(size_t)255;
    return p;
  };
  int*   meta  = (int*)carve(256);
  int*   b2b   = (int*)carve((size_t)3 * NB_ROWS * sizeof(int));
  int*   qrw   = (int*)carve((size_t)3 * 4096 * sizeof(int));
  float* norms = (float*)carve((size_t)3 * NB_ROWS * sizeof(float));
  float* proj  = (float*)carve((size_t)3 * NB_ROWS * DDIM * sizeof(float));  // filled, fp32
  _Float16* bnkh = (_Float16*)carve((size_t)NB_ROWS * DDIM * sizeof(_Float16));
  _Float16* bnkl = (_Float16*)carve((size_t)NB_ROWS * DDIM * sizeof(_Float16));
  char* uni = (char*)carve((size_t)32 * 1024 * 1024);  // Wt splits -> sim -> W1t + h1f16
  if (off > ws_size) return;  // ~168 MB

  // union-region aliases (lifetimes are disjoint, stream-ordered):
  float* sim = (float*)uni;                                  // 1024 x 8192 fp32 (32 MB)
  _Float16* wth[3], *wtl[3];
  for (int m = 0; m < 3; ++m) {
    wth[m] = (_Float16*)(uni + (size_t)m * 8 * 1024 * 1024);
    wtl[m] = (_Float16*)(uni + (size_t)m * 8 * 1024 * 1024 + 4 * 1024 * 1024);
  }
  _Float16* W1t   = (_Float16*)uni;                          // 6 MB, built after sims done
  _Float16* h1f16 = (_Float16*)(uni + (size_t)16 * 1024 * 1024);  // 16 MB

  scan_kernel<<<dim3(3), dim3(256), 0, stream>>>(miss, meta, b2b, qrw);

  for (int m = 0; m < 3; ++m)
    tsplit<<<dim3(64, 32), dim3(32, 8), 0, stream>>>(Wm[m], wth[m], wtl[m], 2048, 1024);

  for (int m = 0; m < 3; ++m)
    gemm_proj_mfma<<<dim3(8, 64), dim3(256), 0, stream>>>(
        xs[m], wth[m], wtl[m], bm[m], proj + (size_t)m * NB_ROWS * DDIM, 2048);

  norms_kernel<<<dim3(NB_ROWS, 3), dim3(256), 0, stream>>>(proj, norms);

  for (int m = 0; m < 3; ++m) {
    build_bnk<<<dim3(NB_ROWS), dim3(256), 0, stream>>>(
        proj + (size_t)m * NB_ROWS * DDIM, norms + m * NB_ROWS, b2b + m * NB_ROWS,
        meta, m, bnkh, bnkl);
    for (int c = 0; c < 4; ++c) {
      gemm_sim_mfma<<<dim3(64, 8), dim3(256), 0, stream>>>(
          bnkh, bnkl, qrw + m * 4096, meta, m, c * 1024, sim);
      topk_fill<<<dim3(1024), dim3(256), 0, stream>>>(
          sim, proj + (size_t)m * NB_ROWS * DDIM, b2b + m * NB_ROWS, qrw + m * 4096,
          meta, miss, m, c * 1024);
    }
  }

  zero_tail<<<dim3(NB_ROWS, 3), dim3(256), 0, stream>>>(miss, meta, proj);
  tsplit<<<dim3(96, 32), dim3(32, 8), 0, stream>>>(W1, W1t, (_Float16*)nullptr, 3072, 1024);
  gemm_h1_mfma<<<dim3(8, 64), dim3(256), 0, stream>>>(proj, W1t, b1, h1f16);
  out_kernel<<<dim3(NB_ROWS), dim3(256), 0, stream>>>(h1f16, W2, b2v, (float*)d_out);
}

// Round 3
// 1989.728 us; speedup vs baseline: 2.1854x; 1.2852x over previous
//
#include <hip/hip_runtime.h>
#include <math.h>

#define NB_ROWS 8192
#define DDIM 1024
#define PSZ ((size_t)NB_ROWS * DDIM)

typedef _Float16 f16x8 __attribute__((ext_vector_type(8)));
typedef _Float16 f16x4 __attribute__((ext_vector_type(4)));
typedef float f32x4 __attribute__((ext_vector_type(4)));

#define LO_SCALE 1024.0f
#define LO_INV (1.0f / 1024.0f)

__device__ __forceinline__ void gload_lds16(const void* g, void* l) {
  __builtin_amdgcn_global_load_lds((const __attribute__((address_space(1))) void*)g,
                                   (__attribute__((address_space(3))) void*)l, 16, 0, 0);
}

__device__ __forceinline__ bool pair_better(float s, int j, float v, int i) {
  return (s > v) || (s == v && j < i);
}

__device__ __forceinline__ f16x8 cvt_hi8(float4 a, float4 b) {
  f16x8 r;
  r[0] = (_Float16)a.x; r[1] = (_Float16)a.y; r[2] = (_Float16)a.z; r[3] = (_Float16)a.w;
  r[4] = (_Float16)b.x; r[5] = (_Float16)b.y; r[6] = (_Float16)b.z; r[7] = (_Float16)b.w;
  return r;
}
__device__ __forceinline__ f16x8 cvt_lo8(float4 a, float4 b, f16x8 h) {
  f16x8 r;
  r[0] = (_Float16)((a.x - (float)h[0]) * LO_SCALE);
  r[1] = (_Float16)((a.y - (float)h[1]) * LO_SCALE);
  r[2] = (_Float16)((a.z - (float)h[2]) * LO_SCALE);
  r[3] = (_Float16)((a.w - (float)h[3]) * LO_SCALE);
  r[4] = (_Float16)((b.x - (float)h[4]) * LO_SCALE);
  r[5] = (_Float16)((b.y - (float)h[5]) * LO_SCALE);
  r[6] = (_Float16)((b.z - (float)h[6]) * LO_SCALE);
  r[7] = (_Float16)((b.w - (float)h[7]) * LO_SCALE);
  return r;
}

// ---------------- scan: bank2batch + query list per modality ----------------
__global__ void scan_kernel(const int* __restrict__ miss, int* __restrict__ meta,
                            int* __restrict__ b2b, int* __restrict__ qrw) {
  const int m = blockIdx.x, t = threadIdx.x, tmod = m + 1;
  __shared__ int cnt[256];
  const int base = t * 32;
  int c = 0;
  for (int i = 0; i < 32; ++i) c += (miss[base + i] != tmod) ? 1 : 0;
  cnt[t] = c; __syncthreads();
  for (int s = 1; s < 256; s <<= 1) {
    int v = (t >= s) ? cnt[t - s] : 0;
    __syncthreads();
    cnt[t] += v;
    __syncthreads();
  }
  const int Nb = cnt[255];
  int pos = cnt[t] - c;
  for (int i = 0; i < 32; ++i) {
    int r = base + i;
    if (miss[r] != tmod) b2b[m * NB_ROWS + (pos++)] = r;
  }
  __syncthreads();
  int q = 0;
  for (int i = 0; i < 32; ++i) {
    int r = base + i;
    q += (miss[r] == tmod && r < Nb) ? 1 : 0;
  }
  cnt[t] = q; __syncthreads();
  for (int s = 1; s < 256; s <<= 1) {
    int v = (t >= s) ? cnt[t - s] : 0;
    __syncthreads();
    cnt[t] += v;
    __syncthreads();
  }
  int nQ = cnt[255];
  if (nQ > 4096) nQ = 4096;
  int qpos = cnt[t] - q;
  for (int i = 0; i < 32; ++i) {
    int r = base + i;
    if (miss[r] == tmod && r < Nb && qpos < 4096) qrw[m * 4096 + (qpos++)] = r;
  }
  for (int i = nQ + t; i < 4096; i += 256) qrw[m * 4096 + i] = 0;  // pad tail
  if (t == 0) { meta[2 * m] = Nb; meta[2 * m + 1] = nQ; }
}

// ------------- transpose + fp16 split: W[K][N] -> Th/Tl[N][K] ---------------
__global__ void tsplit(const float* __restrict__ W, _Float16* __restrict__ Th,
                       _Float16* __restrict__ Tl, int K, int N) {
  __shared__ float tile[32][33];
  const int k0 = blockIdx.x * 32, n0 = blockIdx.y * 32;
  const int tx = threadIdx.x, ty = threadIdx.y;
  for (int i = ty; i < 32; i += 8)
    tile[i][tx] = W[(size_t)(k0 + i) * N + n0 + tx];
  __syncthreads();
  for (int i = ty; i < 32; i += 8) {
    float v = tile[tx][i];
    _Float16 h = (_Float16)v;
    Th[(size_t)(n0 + i) * K + k0 + tx] = h;
    if (Tl) Tl[(size_t)(n0 + i) * K + k0 + tx] = (_Float16)((v - (float)h) * LO_SCALE);
  }
}

// ------------- row-major fp16 split: X fp32 -> Ah/Al (same layout) ----------
__global__ void xsplit(const float* __restrict__ X, _Float16* __restrict__ Ah,
                       _Float16* __restrict__ Al) {
  const size_t idx = ((size_t)blockIdx.x * 256 + threadIdx.x) * 8;
  float4 f0 = *(const float4*)(X + idx);
  float4 f1 = *(const float4*)(X + idx + 4);
  f16x8 hi = cvt_hi8(f0, f1);
  f16x8 lo = cvt_lo8(f0, f1, hi);
  *(f16x8*)(Ah + idx) = hi;
  *(f16x8*)(Al + idx) = lo;
}

// ---- MFMA split GEMM: proj = A(hi/lo)[8192,2048] @ Bt(hi/lo)[1024,2048]^T + bias
// 128x128 tile, BK=32; LDS rows: 8 chunks of 8 halves = [hi0..3 | lo0..3], XOR-(r&7)
__launch_bounds__(256, 2)
__global__ void gemm_proj_mfma(const _Float16* __restrict__ Ah, const _Float16* __restrict__ Al,
                               const _Float16* __restrict__ Bh, const _Float16* __restrict__ Bl,
                               const float* __restrict__ bias,
                               _Float16* __restrict__ Ph, _Float16* __restrict__ Pl) {
  const int K = 2048;
  __shared__ __align__(16) _Float16 Abuf[128 * 64];
  __shared__ __align__(16) _Float16 Bbuf[128 * 64];
  const int t = threadIdx.x;
  const int w = t >> 6, ln = t & 63;
  const int n0 = blockIdx.x * 128, m0 = blockIdx.y * 128;
  const int moff = (w & 1) * 64, noff = (w >> 1) * 64;
  const int lq = ln >> 4, lr = ln & 15;

  const _Float16* as[4]; const _Float16* bs[4];
  _Float16* ad[4]; _Float16* bd[4];
#pragma unroll
  for (int p = 0; p < 4; ++p) {
    int r = p * 32 + w * 8 + (ln >> 3);
    int l = (ln & 7) ^ (r & 7);
    as[p] = (l < 4) ? (Ah + (size_t)(m0 + r) * K + l * 8)
                    : (Al + (size_t)(m0 + r) * K + (l - 4) * 8);
    bs[p] = (l < 4) ? (Bh + (size_t)(n0 + r) * K + l * 8)
                    : (Bl + (size_t)(n0 + r) * K + (l - 4) * 8);
    ad[p] = &Abuf[(p * 32 + w * 8) * 64];
    bd[p] = &Bbuf[(p * 32 + w * 8) * 64];
  }

  f32x4 acc[4][4] = {};
  f32x4 acc2[4][4] = {};

  for (int k0 = 0; k0 < K; k0 += 32) {
#pragma unroll
    for (int p = 0; p < 4; ++p) {
      gload_lds16(as[p] + k0, ad[p]);
      gload_lds16(bs[p] + k0, bd[p]);
    }
    __syncthreads();
    f16x8 ahi[4], alo[4];
#pragma unroll
    for (int mt = 0; mt < 4; ++mt) {
      int r = moff + mt * 16 + lr;
      ahi[mt] = *(f16x8*)&Abuf[r * 64 + ((lq) ^ (r & 7)) * 8];
      alo[mt] = *(f16x8*)&Abuf[r * 64 + ((lq + 4) ^ (r & 7)) * 8];
    }
#pragma unroll
    for (int nt = 0; nt < 4; ++nt) {
      int r = noff + nt * 16 + lr;
      f16x8 bhi = *(f16x8*)&Bbuf[r * 64 + ((lq) ^ (r & 7)) * 8];
      f16x8 blo = *(f16x8*)&Bbuf[r * 64 + ((lq + 4) ^ (r & 7)) * 8];
#pragma unroll
      for (int mt = 0; mt < 4; ++mt) {
        acc[mt][nt]  = __builtin_amdgcn_mfma_f32_16x16x32_f16(ahi[mt], bhi, acc[mt][nt], 0, 0, 0);
        acc2[mt][nt] = __builtin_amdgcn_mfma_f32_16x16x32_f16(ahi[mt], blo, acc2[mt][nt], 0, 0, 0);
        acc2[mt][nt] = __builtin_amdgcn_mfma_f32_16x16x32_f16(alo[mt], bhi, acc2[mt][nt], 0, 0, 0);
      }
    }
    __syncthreads();
  }
#pragma unroll
  for (int nt = 0; nt < 4; ++nt) {
    int col = n0 + noff + nt * 16 + lr;
    float bv = bias[col];
#pragma unroll
    for (int mt = 0; mt < 4; ++mt) {
      int row = m0 + moff + mt * 16 + lq * 4;
#pragma unroll
      for (int r = 0; r < 4; ++r) {
        float v = acc[mt][nt][r] + acc2[mt][nt][r] * LO_INV + bv;
        _Float16 h = (_Float16)v;
        Ph[(size_t)(row + r) * DDIM + col] = h;
        Pl[(size_t)(row + r) * DDIM + col] = (_Float16)((v - (float)h) * LO_SCALE);
      }
    }
  }
}

// ---- MFMA split sim: S[q-qoff, j] = bank[qrw[q]] . bank[j] ------------------
__launch_bounds__(256, 2)
__global__ void gemm_sim_mfma(const _Float16* __restrict__ bh, const _Float16* __restrict__ bl,
                              const int* __restrict__ qrw_m, const int* __restrict__ meta,
                              int mmod, int qoff, float* __restrict__ S) {
  const int Nb = meta[2 * mmod], nQ = meta[2 * mmod + 1];
  const int n0 = blockIdx.x * 128, m0 = blockIdx.y * 128;
  if (qoff + m0 >= nQ || n0 >= Nb) return;
  __shared__ __align__(16) _Float16 Abuf[128 * 64];
  __shared__ __align__(16) _Float16 Bbuf[128 * 64];
  const int t = threadIdx.x;
  const int w = t >> 6, ln = t & 63;
  const int moff = (w & 1) * 64, noff = (w >> 1) * 64;
  const int lq = ln >> 4, lr = ln & 15;

  const _Float16* as[4]; const _Float16* bs[4];
  _Float16* ad[4]; _Float16* bd[4];
#pragma unroll
  for (int p = 0; p < 4; ++p) {
    int r = p * 32 + w * 8 + (ln >> 3);
    int l = (ln & 7) ^ (r & 7);
    int q = qoff + m0 + r; if (q > 4095) q = 4095;
    int arow = qrw_m[q];
    as[p] = (l < 4) ? (bh + (size_t)arow * DDIM + l * 8)
                    : (bl + (size_t)arow * DDIM + (l - 4) * 8);
    bs[p] = (l < 4) ? (bh + (size_t)(n0 + r) * DDIM + l * 8)
                    : (bl + (size_t)(n0 + r) * DDIM + (l - 4) * 8);
    ad[p] = &Abuf[(p * 32 + w * 8) * 64];
    bd[p] = &Bbuf[(p * 32 + w * 8) * 64];
  }

  f32x4 acc[4][4] = {};
  f32x4 acc2[4][4] = {};

  for (int k0 = 0; k0 < DDIM; k0 += 32) {
#pragma unroll
    for (int p = 0; p < 4; ++p) {
      gload_lds16(as[p] + k0, ad[p]);
      gload_lds16(bs[p] + k0, bd[p]);
    }
    __syncthreads();
    f16x8 ahi[4], alo[4];
#pragma unroll
    for (int mt = 0; mt < 4; ++mt) {
      int r = moff + mt * 16 + lr;
      ahi[mt] = *(f16x8*)&Abuf[r * 64 + ((lq) ^ (r & 7)) * 8];
      alo[mt] = *(f16x8*)&Abuf[r * 64 + ((lq + 4) ^ (r & 7)) * 8];
    }
#pragma unroll
    for (int nt = 0; nt < 4; ++nt) {
      int r = noff + nt * 16 + lr;
      f16x8 bhi = *(f16x8*)&Bbuf[r * 64 + ((lq) ^ (r & 7)) * 8];
      f16x8 blo = *(f16x8*)&Bbuf[r * 64 + ((lq + 4) ^ (r & 7)) * 8];
#pragma unroll
      for (int mt = 0; mt < 4; ++mt) {
        acc[mt][nt]  = __builtin_amdgcn_mfma_f32_16x16x32_f16(ahi[mt], bhi, acc[mt][nt], 0, 0, 0);
        acc2[mt][nt] = __builtin_amdgcn_mfma_f32_16x16x32_f16(ahi[mt], blo, acc2[mt][nt], 0, 0, 0);
        acc2[mt][nt] = __builtin_amdgcn_mfma_f32_16x16x32_f16(alo[mt], bhi, acc2[mt][nt], 0, 0, 0);
      }
    }
    __syncthreads();
  }
#pragma unroll
  for (int nt = 0; nt < 4; ++nt) {
    int col = n0 + noff + nt * 16 + lr;
#pragma unroll
    for (int mt = 0; mt < 4; ++mt) {
      int lrow = m0 + moff + mt * 16 + lq * 4;
#pragma unroll
      for (int r = 0; r < 4; ++r) {
        if (qoff + lrow + r < nQ)
          S[(size_t)(lrow + r) * NB_ROWS + col] = acc[mt][nt][r] + acc2[mt][nt][r] * LO_INV;
      }
    }
  }
}

// ---- MFMA fp16 GEMM: H = relu(concat(P hi-planes) @ W1 + b1), fp16 out -----
__launch_bounds__(256, 2)
__global__ void gemm_h1_mfma(const _Float16* __restrict__ P, const _Float16* __restrict__ W1t,
                             const float* __restrict__ bias, _Float16* __restrict__ H) {
  const int K = 3072;
  __shared__ __align__(16) _Float16 Abuf[128 * 64];
  __shared__ __align__(16) _Float16 Bbuf[128 * 64];
  const int t = threadIdx.x;
  const int w = t >> 6, ln = t & 63;
  const int n0 = blockIdx.x * 128, m0 = blockIdx.y * 128;
  const int moff = (w & 1) * 64, noff = (w >> 1) * 64;
  const int lq = ln >> 4, lr = ln & 15;

  size_t aoff[4]; const _Float16* bs[4];
  _Float16* ad[4]; _Float16* bd[4];
#pragma unroll
  for (int p = 0; p < 4; ++p) {
    int r = p * 32 + w * 8 + (ln >> 3);
    int l = (ln & 7) ^ (r & 7);
    aoff[p] = ((size_t)(m0 + r) << 10) + (size_t)(l * 8);  // within hi plane
    bs[p] = W1t + (size_t)(n0 + r) * K + l * 8;
    ad[p] = &Abuf[(p * 32 + w * 8) * 64];
    bd[p] = &Bbuf[(p * 32 + w * 8) * 64];
  }

  f32x4 acc[4][4] = {};

  for (int k0 = 0; k0 < K; k0 += 64) {
    // chunk never crosses a plane boundary: (k0&1023) <= 960, +56 < 1024
    const _Float16* aplane = P + ((size_t)(k0 >> 10) * 2) * PSZ + (k0 & 1023);
#pragma unroll
    for (int p = 0; p < 4; ++p) {
      gload_lds16(aplane + aoff[p], ad[p]);
      gload_lds16(bs[p] + k0, bd[p]);
    }
    __syncthreads();
#pragma unroll
    for (int ks = 0; ks < 2; ++ks) {
      f16x8 a[4];
#pragma unroll
      for (int mt = 0; mt < 4; ++mt) {
        int r = moff + mt * 16 + lr;
        a[mt] = *(f16x8*)&Abuf[r * 64 + ((ks * 4 + lq) ^ (r & 7)) * 8];
      }
#pragma unroll
      for (int nt = 0; nt < 4; ++nt) {
        int r = noff + nt * 16 + lr;
        f16x8 b = *(f16x8*)&Bbuf[r * 64 + ((ks * 4 + lq) ^ (r & 7)) * 8];
#pragma unroll
        for (int mt = 0; mt < 4; ++mt)
          acc[mt][nt] = __builtin_amdgcn_mfma_f32_16x16x32_f16(a[mt], b, acc[mt][nt], 0, 0, 0);
      }
    }
    __syncthreads();
  }
#pragma unroll
  for (int nt = 0; nt < 4; ++nt) {
    int col = n0 + noff + nt * 16 + lr;
    float bv = bias[col];
#pragma unroll
    for (int mt = 0; mt < 4; ++mt) {
      int row = m0 + moff + mt * 16 + lq * 4;
#pragma unroll
      for (int r = 0; r < 4; ++r)
        H[(size_t)(row + r) * DDIM + col] = (_Float16)fmaxf(acc[mt][nt][r] + bv, 0.f);
    }
  }
}

// ---------------- norms, bank build, fill, tail-zero, final ----------------
__global__ void norms_kernel(const _Float16* __restrict__ P, float* __restrict__ norms) {
  const int row = blockIdx.x, m = blockIdx.y, t = threadIdx.x;
  const _Float16* ph = P + (size_t)(2 * m) * PSZ + (size_t)row * DDIM + t * 4;
  const _Float16* pl = ph + PSZ;
  f16x4 h = *(const f16x4*)ph;
  f16x4 l = *(const f16x4*)pl;
  float s = 0.f;
#pragma unroll
  for (int i = 0; i < 4; ++i) {
    float v = (float)h[i] + (float)l[i] * LO_INV;
    s += v * v;
  }
  for (int o = 32; o > 0; o >>= 1) s += __shfl_down(s, o, 64);
  __shared__ float ls[4];
  if ((t & 63) == 0) ls[t >> 6] = s;
  __syncthreads();
  if (t == 0) norms[m * NB_ROWS + row] = fmaxf(sqrtf(ls[0] + ls[1] + ls[2] + ls[3]), 1e-8f);
}

__global__ void build_bnk(const _Float16* __restrict__ Phm, const _Float16* __restrict__ Plm,
                          const float* __restrict__ normsm, const int* __restrict__ b2bm,
                          const int* __restrict__ meta, int mmod,
                          _Float16* __restrict__ bnh, _Float16* __restrict__ bnl) {
  const int j = blockIdx.x, t = threadIdx.x;
  const int Nb = meta[2 * mmod];
  f16x4 hv, lv;
  if (j < Nb) {
    const int b = b2bm[j];
    const float inv = 1.0f / normsm[b];
    f16x4 h = *(const f16x4*)&Phm[(size_t)b * DDIM + t * 4];
    f16x4 l = *(const f16x4*)&Plm[(size_t)b * DDIM + t * 4];
#pragma unroll
    for (int i = 0; i < 4; ++i) {
      float v = ((float)h[i] + (float)l[i] * LO_INV) * inv;
      hv[i] = (_Float16)v;
      lv[i] = (_Float16)((v - (float)hv[i]) * LO_SCALE);
    }
  } else {
    hv = (f16x4)0; lv = (f16x4)0;
  }
  *(f16x4*)&bnh[(size_t)j * DDIM + t * 4] = hv;
  *(f16x4*)&bnl[(size_t)j * DDIM + t * 4] = lv;
}

__global__ void topk_fill(const float* __restrict__ S, _Float16* __restrict__ Phm,
                          _Float16* __restrict__ Plm, const int* __restrict__ b2bm,
                          const int* __restrict__ qrw_m, const int* __restrict__ meta,
                          const int* __restrict__ miss, int mmod, int qoff) {
  const int Nb = meta[2 * mmod], nQ = meta[2 * mmod + 1];
  const int q = qoff + blockIdx.x;
  if (q >= nQ) return;
  const int t = threadIdx.x, tmod = mmod + 1;
  const float* srow = S + (size_t)blockIdx.x * NB_ROWS;
  float v0 = -INFINITY, v1 = -INFINITY, v2 = -INFINITY;
  int i0 = 0x7fffffff, i1 = 0x7fffffff, i2 = 0x7fffffff;
  for (int j = t; j < Nb; j += 256) {
    if (miss[j] == tmod) continue;
    const float s = srow[j];
    if (pair_better(s, j, v0, i0)) { v2 = v1; i2 = i1; v1 = v0; i1 = i0; v0 = s; i0 = j; }
    else if (pair_better(s, j, v1, i1)) { v2 = v1; i2 = i1; v1 = s; i1 = j; }
    else if (pair_better(s, j, v2, i2)) { v2 = s; i2 = j; }
  }
  __shared__ float sv[768];
  __shared__ int si[768];
  sv[t * 3 + 0] = v0; sv[t * 3 + 1] = v1; sv[t * 3 + 2] = v2;
  si[t * 3 + 0] = i0; si[t * 3 + 1] = i1; si[t * 3 + 2] = i2;
  __syncthreads();
  __shared__ float wsh[3];
  __shared__ int idsh[3];
  if (t == 0) {
    float c0 = -INFINITY, c1 = -INFINITY, c2 = -INFINITY;
    int j0 = 0x7fffffff, j1 = 0x7fffffff, j2 = 0x7fffffff;
    for (int e = 0; e < 768; ++e) {
      const float s = sv[e]; const int j = si[e];
      if (pair_better(s, j, c0, j0)) { c2 = c1; j2 = j1; c1 = c0; j1 = j0; c0 = s; j0 = j; }
      else if (pair_better(s, j, c1, j1)) { c2 = c1; j2 = j1; c1 = s; j1 = j; }
      else if (pair_better(s, j, c2, j2)) { c2 = s; j2 = j; }
    }
    if (c0 == -INFINITY) {
      wsh[0] = wsh[1] = wsh[2] = 0.f; idsh[0] = idsh[1] = idsh[2] = 0;
    } else {
      const float e1 = (c1 == -INFINITY) ? 0.f : expf(c1 - c0);
      const float e2 = (c2 == -INFINITY) ? 0.f : expf(c2 - c0);
      const float inv = 1.f / (1.f + e1 + e2);
      wsh[0] = inv; wsh[1] = e1 * inv; wsh[2] = e2 * inv;
      idsh[0] = j0; idsh[1] = (c1 == -INFINITY) ? j0 : j1; idsh[2] = (c2 == -INFINITY) ? j0 : j2;
    }
  }
  __syncthreads();
  const float w0 = wsh[0], w1 = wsh[1], w2 = wsh[2];
  const size_t r0 = (size_t)b2bm[idsh[0]] * DDIM, r1 = (size_t)b2bm[idsh[1]] * DDIM,
               r2 = (size_t)b2bm[idsh[2]] * DDIM;
  const int e = t * 4;
  f16x4 h0 = *(const f16x4*)&Phm[r0 + e], l0 = *(const f16x4*)&Plm[r0 + e];
  f16x4 h1v = *(const f16x4*)&Phm[r1 + e], l1 = *(const f16x4*)&Plm[r1 + e];
  f16x4 h2 = *(const f16x4*)&Phm[r2 + e], l2 = *(const f16x4*)&Plm[r2 + e];
  const size_t qoffp = (size_t)qrw_m[q] * DDIM + e;
  f16x4 oh, ol;
#pragma unroll
  for (int i = 0; i < 4; ++i) {
    float a = (float)h0[i] + (float)l0[i] * LO_INV;
    float b = (float)h1v[i] + (float)l1[i] * LO_INV;
    float c = (float)h2[i] + (float)l2[i] * LO_INV;
    float o = w0 * a + w1 * b + w2 * c;
    oh[i] = (_Float16)o;
    ol[i] = (_Float16)((o - (float)oh[i]) * LO_SCALE);
  }
  *(f16x4*)&Phm[qoffp] = oh;
  *(f16x4*)&Plm[qoffp] = ol;
}

__global__ void zero_tail(const int* __restrict__ miss, const int* __restrict__ meta,
                          _Float16* __restrict__ P) {
  const int row = blockIdx.x, m = blockIdx.y;
  if (miss[row] != m + 1) return;
  if (row < meta[2 * m]) return;
  f16x4 z = (f16x4)0;
  const size_t o = (size_t)row * DDIM + threadIdx.x * 4;
  *(f16x4*)&P[(size_t)(2 * m) * PSZ + o] = z;
  *(f16x4*)&P[(size_t)(2 * m + 1) * PSZ + o] = z;
}

__global__ void out_kernel(const _Float16* __restrict__ h1, const float* __restrict__ w2,
                           const float* __restrict__ b2p, float* __restrict__ out) {
  const int row = blockIdx.x, t = threadIdx.x;
  f16x4 h = *(const f16x4*)&h1[(size_t)row * DDIM + t * 4];
  float4 w = *(const float4*)&w2[t * 4];
  float s = (float)h[0] * w.x + (float)h[1] * w.y + (float)h[2] * w.z + (float)h[3] * w.w;
  for (int o = 32; o > 0; o >>= 1) s += __shfl_down(s, o, 64);
  __shared__ float ls[4];
  if ((t & 63) == 0) ls[t >> 6] = s;
  __syncthreads();
  if (t == 0) out[row] = ls[0] + ls[1] + ls[2] + ls[3] + b2p[0];
}

extern "C" void kernel_launch(void* const* d_in, const int* in_sizes, int n_in,
                              void* d_out, int out_size, void* d_ws, size_t ws_size,
                              hipStream_t stream) {
  const float* xs[3] = {(const float*)d_in[0], (const float*)d_in[1], (const float*)d_in[2]};
  const int* miss = (const int*)d_in[3];
  const float* Wm[3] = {(const float*)d_in[4], (const float*)d_in[6], (const float*)d_in[8]};
  const float* bm[3] = {(const float*)d_in[5], (const float*)d_in[7], (const float*)d_in[9]};
  const float* W1 = (const float*)d_in[10];
  const float* b1 = (const float*)d_in[11];
  const float* W2 = (const float*)d_in[12];
  const float* b2v = (const float*)d_in[13];

  char* base = (char*)d_ws;
  size_t off = 0;
  auto carve = [&](size_t bytes) -> void* {
    void* p = base + off;
    off += (bytes + 255) & ~(size_t)255;
    return p;
  };
  int*   meta  = (int*)carve(256);
  int*   b2b   = (int*)carve((size_t)3 * NB_ROWS * sizeof(int));
  int*   qrw   = (int*)carve((size_t)3 * 4096 * sizeof(int));
  float* norms = (float*)carve((size_t)3 * NB_ROWS * sizeof(float));
  // P: 6 fp16 planes [8192][1024]: (hi,lo) per modality = 96 MB (== fp32 proj)
  _Float16* P = (_Float16*)carve((size_t)6 * PSZ * sizeof(_Float16));
  char* R1 = (char*)carve((size_t)72 * 1024 * 1024);
  if (off > ws_size) return;  // ~168.2 MB

  const size_t MB = 1024 * 1024;
  // phase 1 aliases (per modality, sequential):
  _Float16* A2h = (_Float16*)R1;                 // 32 MB [8192][2048]
  _Float16* A2l = (_Float16*)(R1 + 32 * MB);     // 32 MB
  _Float16* wth = (_Float16*)(R1 + 64 * MB);     // 4 MB [1024][2048]
  _Float16* wtl = (_Float16*)(R1 + 68 * MB);     // 4 MB
  // phase 2 aliases:
  _Float16* bnkh = (_Float16*)R1;                // 16 MB [8192][1024]
  _Float16* bnkl = (_Float16*)(R1 + 16 * MB);    // 16 MB
  float*    sim  = (float*)(R1 + 32 * MB);       // 32 MB [1024][8192]
  // phase 3 aliases:
  _Float16* W1t   = (_Float16*)R1;               // 6 MB [1024][3072]
  _Float16* h1f16 = (_Float16*)(R1 + 32 * MB);   // 16 MB

  scan_kernel<<<dim3(3), dim3(256), 0, stream>>>(miss, meta, b2b, qrw);

  for (int m = 0; m < 3; ++m) {
    tsplit<<<dim3(64, 32), dim3(32, 8), 0, stream>>>(Wm[m], wth, wtl, 2048, 1024);
    xsplit<<<dim3(8192), dim3(256), 0, stream>>>(xs[m], A2h, A2l);
    gemm_proj_mfma<<<dim3(8, 64), dim3(256), 0, stream>>>(
        A2h, A2l, wth, wtl, bm[m], P + (size_t)(2 * m) * PSZ, P + (size_t)(2 * m + 1) * PSZ);
  }

  norms_kernel<<<dim3(NB_ROWS, 3), dim3(256), 0, stream>>>(P, norms);

  for (int m = 0; m < 3; ++m) {
    build_bnk<<<dim3(NB_ROWS), dim3(256), 0, stream>>>(
        P + (size_t)(2 * m) * PSZ, P + (size_t)(2 * m + 1) * PSZ,
        norms + m * NB_ROWS, b2b + m * NB_ROWS, meta, m, bnkh, bnkl);
    for (int c = 0; c < 4; ++c) {
      gemm_sim_mfma<<<dim3(64, 8), dim3(256), 0, stream>>>(
          bnkh, bnkl, qrw + m * 4096, meta, m, c * 1024, sim);
      topk_fill<<<dim3(1024), dim3(256), 0, stream>>>(
          sim, P + (size_t)(2 * m) * PSZ, P + (size_t)(2 * m + 1) * PSZ,
          b2b + m * NB_ROWS, qrw + m * 4096, meta, miss, m, c * 1024);
    }
  }

  zero_tail<<<dim3(NB_ROWS, 3), dim3(256), 0, stream>>>(miss, meta, P);
  tsplit<<<dim3(96, 32), dim3(32, 8), 0, stream>>>(W1, W1t, (_Float16*)nullptr, 3072, 1024);
  gemm_h1_mfma<<<dim3(8, 64), dim3(256), 0, stream>>>(P, W1t, b1, h1f16);
  out_kernel<<<dim3(NB_ROWS), dim3(256), 0, stream>>>(h1f16, W2, b2v, (float*)d_out);
}

// Round 4
// 1299.620 us; speedup vs baseline: 3.3459x; 1.5310x over previous
//
#include <hip/hip_runtime.h>
#include <math.h>

#define NB_ROWS 8192
#define DDIM 1024
#define PSZ ((size_t)NB_ROWS * DDIM)

typedef _Float16 f16x8 __attribute__((ext_vector_type(8)));
typedef _Float16 f16x4 __attribute__((ext_vector_type(4)));
typedef float f32x4 __attribute__((ext_vector_type(4)));

#define LO_SCALE 1024.0f
#define LO_INV (1.0f / 1024.0f)

__device__ __forceinline__ void gload_lds16(const void* g, void* l) {
  __builtin_amdgcn_global_load_lds((const __attribute__((address_space(1))) void*)g,
                                   (__attribute__((address_space(3))) void*)l, 16, 0, 0);
}

__device__ __forceinline__ bool pair_better(float s, int j, float v, int i) {
  return (s > v) || (s == v && j < i);
}

__device__ __forceinline__ void upd3(float s, int jj, float& v0, int& i0,
                                     float& v1, int& i1, float& v2, int& i2) {
  if (pair_better(s, jj, v0, i0)) { v2 = v1; i2 = i1; v1 = v0; i1 = i0; v0 = s; i0 = jj; }
  else if (pair_better(s, jj, v1, i1)) { v2 = v1; i2 = i1; v1 = s; i1 = jj; }
  else if (pair_better(s, jj, v2, i2)) { v2 = s; i2 = jj; }
}

// merge sorted triple (v) with sorted triple (b) -> sorted top-3 in (v)
__device__ __forceinline__ void merge3(float& v0, int& i0, float& v1, int& i1,
                                       float& v2, int& i2, float b0, int jb0,
                                       float b1, int jb1, float b2, int jb2) {
  float r0, r1, r2; int q0, q1, q2;
  if (pair_better(v0, i0, b0, jb0)) {
    r0 = v0; q0 = i0;
    if (pair_better(v1, i1, b0, jb0)) {
      r1 = v1; q1 = i1;
      if (pair_better(v2, i2, b0, jb0)) { r2 = v2; q2 = i2; } else { r2 = b0; q2 = jb0; }
    } else {
      r1 = b0; q1 = jb0;
      if (pair_better(v1, i1, b1, jb1)) { r2 = v1; q2 = i1; } else { r2 = b1; q2 = jb1; }
    }
  } else {
    r0 = b0; q0 = jb0;
    if (pair_better(v0, i0, b1, jb1)) {
      r1 = v0; q1 = i0;
      if (pair_better(v1, i1, b1, jb1)) { r2 = v1; q2 = i1; } else { r2 = b1; q2 = jb1; }
    } else {
      r1 = b1; q1 = jb1;
      if (pair_better(v0, i0, b2, jb2)) { r2 = v0; q2 = i0; } else { r2 = b2; q2 = jb2; }
    }
  }
  v0 = r0; i0 = q0; v1 = r1; i1 = q1; v2 = r2; i2 = q2;
}

// ---------------- scan: bank2batch + query list per modality ----------------
__global__ void scan_kernel(const int* __restrict__ miss, int* __restrict__ meta,
                            int* __restrict__ b2b, int* __restrict__ qrw) {
  const int m = blockIdx.x, t = threadIdx.x, tmod = m + 1;
  __shared__ int cnt[256];
  const int base = t * 32;
  int c = 0;
  for (int i = 0; i < 32; ++i) c += (miss[base + i] != tmod) ? 1 : 0;
  cnt[t] = c; __syncthreads();
  for (int s = 1; s < 256; s <<= 1) {
    int v = (t >= s) ? cnt[t - s] : 0;
    __syncthreads();
    cnt[t] += v;
    __syncthreads();
  }
  const int Nb = cnt[255];
  int pos = cnt[t] - c;
  for (int i = 0; i < 32; ++i) {
    int r = base + i;
    if (miss[r] != tmod) b2b[m * NB_ROWS + (pos++)] = r;
  }
  __syncthreads();
  int q = 0;
  for (int i = 0; i < 32; ++i) {
    int r = base + i;
    q += (miss[r] == tmod && r < Nb) ? 1 : 0;
  }
  cnt[t] = q; __syncthreads();
  for (int s = 1; s < 256; s <<= 1) {
    int v = (t >= s) ? cnt[t - s] : 0;
    __syncthreads();
    cnt[t] += v;
    __syncthreads();
  }
  int nQ = cnt[255];
  if (nQ > 4096) nQ = 4096;
  int qpos = cnt[t] - q;
  for (int i = 0; i < 32; ++i) {
    int r = base + i;
    if (miss[r] == tmod && r < Nb && qpos < 4096) qrw[m * 4096 + (qpos++)] = r;
  }
  for (int i = nQ + t; i < 4096; i += 256) qrw[m * 4096 + i] = 0;  // pad tail
  if (t == 0) { meta[2 * m] = Nb; meta[2 * m + 1] = nQ; }
}

// ------------- transpose + fp16 split: W[K][N] -> Th/Tl[N][K] ---------------
__global__ void tsplit(const float* __restrict__ W, _Float16* __restrict__ Th,
                       _Float16* __restrict__ Tl, int K, int N) {
  __shared__ float tile[32][33];
  const int k0 = blockIdx.x * 32, n0 = blockIdx.y * 32;
  const int tx = threadIdx.x, ty = threadIdx.y;
  for (int i = ty; i < 32; i += 8)
    tile[i][tx] = W[(size_t)(k0 + i) * N + n0 + tx];
  __syncthreads();
  for (int i = ty; i < 32; i += 8) {
    float v = tile[tx][i];
    _Float16 h = (_Float16)v;
    Th[(size_t)(n0 + i) * K + k0 + tx] = h;
    if (Tl) Tl[(size_t)(n0 + i) * K + k0 + tx] = (_Float16)((v - (float)h) * LO_SCALE);
  }
}

__device__ __forceinline__ f16x8 cvt_hi8(float4 a, float4 b) {
  f16x8 r;
  r[0] = (_Float16)a.x; r[1] = (_Float16)a.y; r[2] = (_Float16)a.z; r[3] = (_Float16)a.w;
  r[4] = (_Float16)b.x; r[5] = (_Float16)b.y; r[6] = (_Float16)b.z; r[7] = (_Float16)b.w;
  return r;
}
__device__ __forceinline__ f16x8 cvt_lo8(float4 a, float4 b, f16x8 h) {
  f16x8 r;
  r[0] = (_Float16)((a.x - (float)h[0]) * LO_SCALE);
  r[1] = (_Float16)((a.y - (float)h[1]) * LO_SCALE);
  r[2] = (_Float16)((a.z - (float)h[2]) * LO_SCALE);
  r[3] = (_Float16)((a.w - (float)h[3]) * LO_SCALE);
  r[4] = (_Float16)((b.x - (float)h[4]) * LO_SCALE);
  r[5] = (_Float16)((b.y - (float)h[5]) * LO_SCALE);
  r[6] = (_Float16)((b.z - (float)h[6]) * LO_SCALE);
  r[7] = (_Float16)((b.w - (float)h[7]) * LO_SCALE);
  return r;
}

// ------------- row-major fp16 split: X fp32 -> Ah/Al (same layout) ----------
__global__ void xsplit(const float* __restrict__ X, _Float16* __restrict__ Ah,
                       _Float16* __restrict__ Al) {
  const size_t idx = ((size_t)blockIdx.x * 256 + threadIdx.x) * 8;
  float4 f0 = *(const float4*)(X + idx);
  float4 f1 = *(const float4*)(X + idx + 4);
  f16x8 hi = cvt_hi8(f0, f1);
  f16x8 lo = cvt_lo8(f0, f1, hi);
  *(f16x8*)(Ah + idx) = hi;
  *(f16x8*)(Al + idx) = lo;
}

// ---- MFMA split GEMM: proj = A(hi/lo)[8192,2048] @ Bt(hi/lo)[1024,2048]^T + bias
__launch_bounds__(256, 2)
__global__ void gemm_proj_mfma(const _Float16* __restrict__ Ah, const _Float16* __restrict__ Al,
                               const _Float16* __restrict__ Bh, const _Float16* __restrict__ Bl,
                               const float* __restrict__ bias,
                               _Float16* __restrict__ Ph, _Float16* __restrict__ Pl) {
  const int K = 2048;
  __shared__ __align__(16) _Float16 Abuf[128 * 64];
  __shared__ __align__(16) _Float16 Bbuf[128 * 64];
  const int t = threadIdx.x;
  const int w = t >> 6, ln = t & 63;
  const int n0 = blockIdx.x * 128, m0 = blockIdx.y * 128;
  const int moff = (w & 1) * 64, noff = (w >> 1) * 64;
  const int lq = ln >> 4, lr = ln & 15;

  const _Float16* as[4]; const _Float16* bs[4];
  _Float16* ad[4]; _Float16* bd[4];
#pragma unroll
  for (int p = 0; p < 4; ++p) {
    int r = p * 32 + w * 8 + (ln >> 3);
    int l = (ln & 7) ^ (r & 7);
    as[p] = (l < 4) ? (Ah + (size_t)(m0 + r) * K + l * 8)
                    : (Al + (size_t)(m0 + r) * K + (l - 4) * 8);
    bs[p] = (l < 4) ? (Bh + (size_t)(n0 + r) * K + l * 8)
                    : (Bl + (size_t)(n0 + r) * K + (l - 4) * 8);
    ad[p] = &Abuf[(p * 32 + w * 8) * 64];
    bd[p] = &Bbuf[(p * 32 + w * 8) * 64];
  }

  f32x4 acc[4][4] = {};
  f32x4 acc2[4][4] = {};

  for (int k0 = 0; k0 < K; k0 += 32) {
#pragma unroll
    for (int p = 0; p < 4; ++p) {
      gload_lds16(as[p] + k0, ad[p]);
      gload_lds16(bs[p] + k0, bd[p]);
    }
    __syncthreads();
    f16x8 ahi[4], alo[4];
#pragma unroll
    for (int mt = 0; mt < 4; ++mt) {
      int r = moff + mt * 16 + lr;
      ahi[mt] = *(f16x8*)&Abuf[r * 64 + ((lq) ^ (r & 7)) * 8];
      alo[mt] = *(f16x8*)&Abuf[r * 64 + ((lq + 4) ^ (r & 7)) * 8];
    }
#pragma unroll
    for (int nt = 0; nt < 4; ++nt) {
      int r = noff + nt * 16 + lr;
      f16x8 bhi = *(f16x8*)&Bbuf[r * 64 + ((lq) ^ (r & 7)) * 8];
      f16x8 blo = *(f16x8*)&Bbuf[r * 64 + ((lq + 4) ^ (r & 7)) * 8];
#pragma unroll
      for (int mt = 0; mt < 4; ++mt) {
        acc[mt][nt]  = __builtin_amdgcn_mfma_f32_16x16x32_f16(ahi[mt], bhi, acc[mt][nt], 0, 0, 0);
        acc2[mt][nt] = __builtin_amdgcn_mfma_f32_16x16x32_f16(ahi[mt], blo, acc2[mt][nt], 0, 0, 0);
        acc2[mt][nt] = __builtin_amdgcn_mfma_f32_16x16x32_f16(alo[mt], bhi, acc2[mt][nt], 0, 0, 0);
      }
    }
    __syncthreads();
  }
#pragma unroll
  for (int nt = 0; nt < 4; ++nt) {
    int col = n0 + noff + nt * 16 + lr;
    float bv = bias[col];
#pragma unroll
    for (int mt = 0; mt < 4; ++mt) {
      int row = m0 + moff + mt * 16 + lq * 4;
#pragma unroll
      for (int r = 0; r < 4; ++r) {
        float v = acc[mt][nt][r] + acc2[mt][nt][r] * LO_INV + bv;
        _Float16 h = (_Float16)v;
        Ph[(size_t)(row + r) * DDIM + col] = h;
        Pl[(size_t)(row + r) * DDIM + col] = (_Float16)((v - (float)h) * LO_SCALE);
      }
    }
  }
}

// ---- MFMA split sim: S[q-qoff, j] = bank[qrw[q]] . bank[j], pre-masked -----
__launch_bounds__(256, 2)
__global__ void gemm_sim_mfma(const _Float16* __restrict__ bh, const _Float16* __restrict__ bl,
                              const int* __restrict__ qrw_m, const int* __restrict__ meta,
                              const int* __restrict__ miss, int mmod, int qoff,
                              float* __restrict__ S) {
  const int Nb = meta[2 * mmod], nQ = meta[2 * mmod + 1];
  const int n0 = blockIdx.x * 128, m0 = blockIdx.y * 128;
  if (qoff + m0 >= nQ || n0 >= Nb) return;
  __shared__ __align__(16) _Float16 Abuf[128 * 64];
  __shared__ __align__(16) _Float16 Bbuf[128 * 64];
  const int t = threadIdx.x;
  const int w = t >> 6, ln = t & 63;
  const int moff = (w & 1) * 64, noff = (w >> 1) * 64;
  const int lq = ln >> 4, lr = ln & 15;

  const _Float16* as[4]; const _Float16* bs[4];
  _Float16* ad[4]; _Float16* bd[4];
#pragma unroll
  for (int p = 0; p < 4; ++p) {
    int r = p * 32 + w * 8 + (ln >> 3);
    int l = (ln & 7) ^ (r & 7);
    int q = qoff + m0 + r; if (q > 4095) q = 4095;
    int arow = qrw_m[q];
    as[p] = (l < 4) ? (bh + (size_t)arow * DDIM + l * 8)
                    : (bl + (size_t)arow * DDIM + (l - 4) * 8);
    bs[p] = (l < 4) ? (bh + (size_t)(n0 + r) * DDIM + l * 8)
                    : (bl + (size_t)(n0 + r) * DDIM + (l - 4) * 8);
    ad[p] = &Abuf[(p * 32 + w * 8) * 64];
    bd[p] = &Bbuf[(p * 32 + w * 8) * 64];
  }

  f32x4 acc[4][4] = {};
  f32x4 acc2[4][4] = {};

  for (int k0 = 0; k0 < DDIM; k0 += 32) {
#pragma unroll
    for (int p = 0; p < 4; ++p) {
      gload_lds16(as[p] + k0, ad[p]);
      gload_lds16(bs[p] + k0, bd[p]);
    }
    __syncthreads();
    f16x8 ahi[4], alo[4];
#pragma unroll
    for (int mt = 0; mt < 4; ++mt) {
      int r = moff + mt * 16 + lr;
      ahi[mt] = *(f16x8*)&Abuf[r * 64 + ((lq) ^ (r & 7)) * 8];
      alo[mt] = *(f16x8*)&Abuf[r * 64 + ((lq + 4) ^ (r & 7)) * 8];
    }
#pragma unroll
    for (int nt = 0; nt < 4; ++nt) {
      int r = noff + nt * 16 + lr;
      f16x8 bhi = *(f16x8*)&Bbuf[r * 64 + ((lq) ^ (r & 7)) * 8];
      f16x8 blo = *(f16x8*)&Bbuf[r * 64 + ((lq + 4) ^ (r & 7)) * 8];
#pragma unroll
      for (int mt = 0; mt < 4; ++mt) {
        acc[mt][nt]  = __builtin_amdgcn_mfma_f32_16x16x32_f16(ahi[mt], bhi, acc[mt][nt], 0, 0, 0);
        acc2[mt][nt] = __builtin_amdgcn_mfma_f32_16x16x32_f16(ahi[mt], blo, acc2[mt][nt], 0, 0, 0);
        acc2[mt][nt] = __builtin_amdgcn_mfma_f32_16x16x32_f16(alo[mt], bhi, acc2[mt][nt], 0, 0, 0);
      }
    }
    __syncthreads();
  }
#pragma unroll
  for (int nt = 0; nt < 4; ++nt) {
    int col = n0 + noff + nt * 16 + lr;
    const bool colok = (col < Nb) && (miss[col] != mmod + 1);  // col_valid, batch-indexed (source bug kept)
#pragma unroll
    for (int mt = 0; mt < 4; ++mt) {
      int lrow = m0 + moff + mt * 16 + lq * 4;
#pragma unroll
      for (int r = 0; r < 4; ++r) {
        if (qoff + lrow + r < nQ)
          S[(size_t)(lrow + r) * NB_ROWS + col] =
              colok ? (acc[mt][nt][r] + acc2[mt][nt][r] * LO_INV) : -INFINITY;
      }
    }
  }
}

// ---- MFMA fp16 GEMM: H = relu(concat(P hi-planes) @ W1 + b1), fp16 out -----
__launch_bounds__(256, 2)
__global__ void gemm_h1_mfma(const _Float16* __restrict__ P, const _Float16* __restrict__ W1t,
                             const float* __restrict__ bias, _Float16* __restrict__ H) {
  const int K = 3072;
  __shared__ __align__(16) _Float16 Abuf[128 * 64];
  __shared__ __align__(16) _Float16 Bbuf[128 * 64];
  const int t = threadIdx.x;
  const int w = t >> 6, ln = t & 63;
  const int n0 = blockIdx.x * 128, m0 = blockIdx.y * 128;
  const int moff = (w & 1) * 64, noff = (w >> 1) * 64;
  const int lq = ln >> 4, lr = ln & 15;

  size_t aoff[4]; const _Float16* bs[4];
  _Float16* ad[4]; _Float16* bd[4];
#pragma unroll
  for (int p = 0; p < 4; ++p) {
    int r = p * 32 + w * 8 + (ln >> 3);
    int l = (ln & 7) ^ (r & 7);
    aoff[p] = ((size_t)(m0 + r) << 10) + (size_t)(l * 8);
    bs[p] = W1t + (size_t)(n0 + r) * K + l * 8;
    ad[p] = &Abuf[(p * 32 + w * 8) * 64];
    bd[p] = &Bbuf[(p * 32 + w * 8) * 64];
  }

  f32x4 acc[4][4] = {};

  for (int k0 = 0; k0 < K; k0 += 64) {
    const _Float16* aplane = P + ((size_t)(k0 >> 10) * 2) * PSZ + (k0 & 1023);
#pragma unroll
    for (int p = 0; p < 4; ++p) {
      gload_lds16(aplane + aoff[p], ad[p]);
      gload_lds16(bs[p] + k0, bd[p]);
    }
    __syncthreads();
#pragma unroll
    for (int ks = 0; ks < 2; ++ks) {
      f16x8 a[4];
#pragma unroll
      for (int mt = 0; mt < 4; ++mt) {
        int r = moff + mt * 16 + lr;
        a[mt] = *(f16x8*)&Abuf[r * 64 + ((ks * 4 + lq) ^ (r & 7)) * 8];
      }
#pragma unroll
      for (int nt = 0; nt < 4; ++nt) {
        int r = noff + nt * 16 + lr;
        f16x8 b = *(f16x8*)&Bbuf[r * 64 + ((ks * 4 + lq) ^ (r & 7)) * 8];
#pragma unroll
        for (int mt = 0; mt < 4; ++mt)
          acc[mt][nt] = __builtin_amdgcn_mfma_f32_16x16x32_f16(a[mt], b, acc[mt][nt], 0, 0, 0);
      }
    }
    __syncthreads();
  }
#pragma unroll
  for (int nt = 0; nt < 4; ++nt) {
    int col = n0 + noff + nt * 16 + lr;
    float bv = bias[col];
#pragma unroll
    for (int mt = 0; mt < 4; ++mt) {
      int row = m0 + moff + mt * 16 + lq * 4;
#pragma unroll
      for (int r = 0; r < 4; ++r)
        H[(size_t)(row + r) * DDIM + col] = (_Float16)fmaxf(acc[mt][nt][r] + bv, 0.f);
    }
  }
}

// ---------------- bank build (fused norm), fill, tail-zero, final -----------
__global__ void build_bnk(const _Float16* __restrict__ Phm, const _Float16* __restrict__ Plm,
                          const int* __restrict__ b2bm, const int* __restrict__ meta,
                          int mmod, _Float16* __restrict__ bnh, _Float16* __restrict__ bnl) {
  const int j = blockIdx.x, t = threadIdx.x;
  const int Nb = meta[2 * mmod];
  const size_t o = (size_t)j * DDIM + t * 4;
  if (j >= Nb) {
    *(f16x4*)&bnh[o] = (f16x4)0;
    *(f16x4*)&bnl[o] = (f16x4)0;
    return;
  }
  const int b = b2bm[j];
  f16x4 h = *(const f16x4*)&Phm[(size_t)b * DDIM + t * 4];
  f16x4 l = *(const f16x4*)&Plm[(size_t)b * DDIM + t * 4];
  float v[4]; float s = 0.f;
#pragma unroll
  for (int i = 0; i < 4; ++i) {
    v[i] = (float)h[i] + (float)l[i] * LO_INV;
    s += v[i] * v[i];
  }
  for (int ofs = 32; ofs > 0; ofs >>= 1) s += __shfl_down(s, ofs, 64);
  __shared__ float ls[4];
  if ((t & 63) == 0) ls[t >> 6] = s;
  __syncthreads();
  const float inv = 1.0f / fmaxf(sqrtf(ls[0] + ls[1] + ls[2] + ls[3]), 1e-8f);
  f16x4 hv, lv;
#pragma unroll
  for (int i = 0; i < 4; ++i) {
    float x = v[i] * inv;
    hv[i] = (_Float16)x;
    lv[i] = (_Float16)((x - (float)hv[i]) * LO_SCALE);
  }
  *(f16x4*)&bnh[o] = hv;
  *(f16x4*)&bnl[o] = lv;
}

__launch_bounds__(256)
__global__ void topk_fill(const float* __restrict__ S, _Float16* __restrict__ Phm,
                          _Float16* __restrict__ Plm, const int* __restrict__ b2bm,
                          const int* __restrict__ qrw_m, const int* __restrict__ meta,
                          int mmod, int qoff) {
  const int Nb = meta[2 * mmod], nQ = meta[2 * mmod + 1];
  const int q = qoff + blockIdx.x;
  if (q >= nQ) return;
  const int t = threadIdx.x;
  const float4* srow4 = (const float4*)(S + (size_t)blockIdx.x * NB_ROWS);
  float v0 = -INFINITY, v1 = -INFINITY, v2 = -INFINITY;
  int i0 = 0x7fffffff, i1 = 0x7fffffff, i2 = 0x7fffffff;
#pragma unroll
  for (int it = 0; it < 8; ++it) {
    const int j = it * 1024 + t * 4;
    float4 f = srow4[j >> 2];
    float e0 = (j + 0 < Nb) ? f.x : -INFINITY;  // guard unwritten tail (poison)
    float e1 = (j + 1 < Nb) ? f.y : -INFINITY;
    float e2 = (j + 2 < Nb) ? f.z : -INFINITY;
    float e3 = (j + 3 < Nb) ? f.w : -INFINITY;
    upd3(e0, j + 0, v0, i0, v1, i1, v2, i2);
    upd3(e1, j + 1, v0, i0, v1, i1, v2, i2);
    upd3(e2, j + 2, v0, i0, v1, i1, v2, i2);
    upd3(e3, j + 3, v0, i0, v1, i1, v2, i2);
  }
  __shared__ float sv0[256], sv1[256], sv2[256];
  __shared__ int   si0[256], si1[256], si2[256];
  sv0[t] = v0; sv1[t] = v1; sv2[t] = v2;
  si0[t] = i0; si1[t] = i1; si2[t] = i2;
  __syncthreads();
  for (int n = 128; n >= 1; n >>= 1) {
    if (t < n) {
      merge3(v0, i0, v1, i1, v2, i2,
             sv0[t + n], si0[t + n], sv1[t + n], si1[t + n], sv2[t + n], si2[t + n]);
      sv0[t] = v0; sv1[t] = v1; sv2[t] = v2;
      si0[t] = i0; si1[t] = i1; si2[t] = i2;
    }
    __syncthreads();
  }
  __shared__ float wsh[3];
  __shared__ int idsh[3];
  if (t == 0) {
    if (v0 == -INFINITY) {
      wsh[0] = wsh[1] = wsh[2] = 0.f; idsh[0] = idsh[1] = idsh[2] = 0;
    } else {
      const float e1w = (v1 == -INFINITY) ? 0.f : expf(v1 - v0);
      const float e2w = (v2 == -INFINITY) ? 0.f : expf(v2 - v0);
      const float inv = 1.f / (1.f + e1w + e2w);
      wsh[0] = inv; wsh[1] = e1w * inv; wsh[2] = e2w * inv;
      idsh[0] = i0;
      idsh[1] = (v1 == -INFINITY) ? i0 : i1;
      idsh[2] = (v2 == -INFINITY) ? i0 : i2;
    }
  }
  __syncthreads();
  const float w0 = wsh[0], w1 = wsh[1], w2 = wsh[2];
  const size_t r0 = (size_t)b2bm[idsh[0]] * DDIM, r1 = (size_t)b2bm[idsh[1]] * DDIM,
               r2 = (size_t)b2bm[idsh[2]] * DDIM;
  const int e = t * 4;
  f16x4 h0 = *(const f16x4*)&Phm[r0 + e], l0 = *(const f16x4*)&Plm[r0 + e];
  f16x4 h1v = *(const f16x4*)&Phm[r1 + e], l1 = *(const f16x4*)&Plm[r1 + e];
  f16x4 h2 = *(const f16x4*)&Phm[r2 + e], l2 = *(const f16x4*)&Plm[r2 + e];
  const size_t qoffp = (size_t)qrw_m[q] * DDIM + e;
  f16x4 oh, ol;
#pragma unroll
  for (int i = 0; i < 4; ++i) {
    float a = (float)h0[i] + (float)l0[i] * LO_INV;
    float b = (float)h1v[i] + (float)l1[i] * LO_INV;
    float c = (float)h2[i] + (float)l2[i] * LO_INV;
    float o = w0 * a + w1 * b + w2 * c;
    oh[i] = (_Float16)o;
    ol[i] = (_Float16)((o - (float)oh[i]) * LO_SCALE);
  }
  *(f16x4*)&Phm[qoffp] = oh;
  *(f16x4*)&Plm[qoffp] = ol;
}

__global__ void zero_tail(const int* __restrict__ miss, const int* __restrict__ meta,
                          _Float16* __restrict__ P) {
  const int row = blockIdx.x, m = blockIdx.y;
  if (miss[row] != m + 1) return;
  if (row < meta[2 * m]) return;
  f16x4 z = (f16x4)0;
  const size_t o = (size_t)row * DDIM + threadIdx.x * 4;
  *(f16x4*)&P[(size_t)(2 * m) * PSZ + o] = z;
  *(f16x4*)&P[(size_t)(2 * m + 1) * PSZ + o] = z;
}

__global__ void out_kernel(const _Float16* __restrict__ h1, const float* __restrict__ w2,
                           const float* __restrict__ b2p, float* __restrict__ out) {
  const int row = blockIdx.x, t = threadIdx.x;
  f16x4 h = *(const f16x4*)&h1[(size_t)row * DDIM + t * 4];
  float4 w = *(const float4*)&w2[t * 4];
  float s = (float)h[0] * w.x + (float)h[1] * w.y + (float)h[2] * w.z + (float)h[3] * w.w;
  for (int o = 32; o > 0; o >>= 1) s += __shfl_down(s, o, 64);
  __shared__ float ls[4];
  if ((t & 63) == 0) ls[t >> 6] = s;
  __syncthreads();
  if (t == 0) out[row] = ls[0] + ls[1] + ls[2] + ls[3] + b2p[0];
}

extern "C" void kernel_launch(void* const* d_in, const int* in_sizes, int n_in,
                              void* d_out, int out_size, void* d_ws, size_t ws_size,
                              hipStream_t stream) {
  const float* xs[3] = {(const float*)d_in[0], (const float*)d_in[1], (const float*)d_in[2]};
  const int* miss = (const int*)d_in[3];
  const float* Wm[3] = {(const float*)d_in[4], (const float*)d_in[6], (const float*)d_in[8]};
  const float* bm[3] = {(const float*)d_in[5], (const float*)d_in[7], (const float*)d_in[9]};
  const float* W1 = (const float*)d_in[10];
  const float* b1 = (const float*)d_in[11];
  const float* W2 = (const float*)d_in[12];
  const float* b2v = (const float*)d_in[13];

  char* base = (char*)d_ws;
  size_t off = 0;
  auto carve = [&](size_t bytes) -> void* {
    void* p = base + off;
    off += (bytes + 255) & ~(size_t)255;
    return p;
  };
  int*   meta  = (int*)carve(256);
  int*   b2b   = (int*)carve((size_t)3 * NB_ROWS * sizeof(int));
  int*   qrw   = (int*)carve((size_t)3 * 4096 * sizeof(int));
  _Float16* P = (_Float16*)carve((size_t)6 * PSZ * sizeof(_Float16));  // 96 MB
  char* R1 = (char*)carve((size_t)72 * 1024 * 1024);
  if (off > ws_size) return;  // ~168.1 MB

  const size_t MB = 1024 * 1024;
  // phase 1 aliases:
  _Float16* A2h = (_Float16*)R1;                 // 32 MB
  _Float16* A2l = (_Float16*)(R1 + 32 * MB);     // 32 MB
  _Float16* wth = (_Float16*)(R1 + 64 * MB);     // 4 MB
  _Float16* wtl = (_Float16*)(R1 + 68 * MB);     // 4 MB
  // phase 2 aliases:
  _Float16* bnkh = (_Float16*)R1;                // 16 MB
  _Float16* bnkl = (_Float16*)(R1 + 16 * MB);    // 16 MB
  float*    sim  = (float*)(R1 + 32 * MB);       // 32 MB
  // phase 3 aliases:
  _Float16* W1t   = (_Float16*)R1;               // 6 MB
  _Float16* h1f16 = (_Float16*)(R1 + 32 * MB);   // 16 MB

  scan_kernel<<<dim3(3), dim3(256), 0, stream>>>(miss, meta, b2b, qrw);

  for (int m = 0; m < 3; ++m) {
    tsplit<<<dim3(64, 32), dim3(32, 8), 0, stream>>>(Wm[m], wth, wtl, 2048, 1024);
    xsplit<<<dim3(8192), dim3(256), 0, stream>>>(xs[m], A2h, A2l);
    gemm_proj_mfma<<<dim3(8, 64), dim3(256), 0, stream>>>(
        A2h, A2l, wth, wtl, bm[m], P + (size_t)(2 * m) * PSZ, P + (size_t)(2 * m + 1) * PSZ);
  }

  for (int m = 0; m < 3; ++m) {
    build_bnk<<<dim3(NB_ROWS), dim3(256), 0, stream>>>(
        P + (size_t)(2 * m) * PSZ, P + (size_t)(2 * m + 1) * PSZ,
        b2b + m * NB_ROWS, meta, m, bnkh, bnkl);
    for (int c = 0; c < 4; ++c) {
      gemm_sim_mfma<<<dim3(64, 8), dim3(256), 0, stream>>>(
          bnkh, bnkl, qrw + m * 4096, meta, miss, m, c * 1024, sim);
      topk_fill<<<dim3(1024), dim3(256), 0, stream>>>(
          sim, P + (size_t)(2 * m) * PSZ, P + (size_t)(2 * m + 1) * PSZ,
          b2b + m * NB_ROWS, qrw + m * 4096, meta, m, c * 1024);
    }
  }

  zero_tail<<<dim3(NB_ROWS, 3), dim3(256), 0, stream>>>(miss, meta, P);
  tsplit<<<dim3(96, 32), dim3(32, 8), 0, stream>>>(W1, W1t, (_Float16*)nullptr, 3072, 1024);
  gemm_h1_mfma<<<dim3(8, 64), dim3(256), 0, stream>>>(P, W1t, b1, h1f16);
  out_kernel<<<dim3(NB_ROWS), dim3(256), 0, stream>>>(h1f16, W2, b2v, (float*)d_out);
}